// Round 3
// baseline (1699.300 us; speedup 1.0000x reference)
//
#include <hip/hip_runtime.h>
#include <math.h>

#define Bn  16
#define Hd  1024
#define COn 512
#define NVn 2048
#define NQn 2048

#define BM 128
#define BN 128
#define BK 16
#define LDT 132

typedef unsigned short u16;
typedef __attribute__((ext_vector_type(8))) short short8;
typedef __attribute__((ext_vector_type(4))) float floatx4;

__device__ __forceinline__ float fast_tanh(float x) {
    float ax = fabsf(x);
    float e  = __expf(2.0f * ax);
    float t  = 1.0f - 2.0f / (e + 1.0f);
    return copysignf(t, x);
}

__device__ __forceinline__ u16 f32_to_bf16(float x) {
    unsigned u = __float_as_uint(x);
    unsigned r = (u + 0x7fffu + ((u >> 16) & 1u)) >> 16;   // RNE, finite inputs
    return (u16)r;
}
__device__ __forceinline__ float bf16_to_f32(u16 h) {
    return __uint_as_float(((unsigned)h) << 16);
}

// async global->LDS, 16B per lane. LDS dest is wave-uniform base + lane*16.
__device__ __forceinline__ void gload16(const u16* g, u16* l) {
    __builtin_amdgcn_global_load_lds(
        (__attribute__((address_space(1))) void*)(g),
        (__attribute__((address_space(3))) void*)(l), 16, 0, 0);
}

// ================= 256x256 8-wave phase-split bf16x3 GEMM =================
// C = A*B (+bias): A [M,K] k-contig hi/lo, B TRANSPOSED [N,K] k-contig hi/lo.
// grid = gx*gy*Bn (1D, XCD-swizzled), block = 512.  M = gy*256, N = gx*256,
// K mult of 32 (>=64).
// LDS layout: [buf][mat][kslot(16B)][row-slot*16B], row-slot = row ^ (2*kslot)
// -> quarter/half-wave ds_read_b128 spreads over all 32 banks (2-way max).
// Staging keeps LDS dest linear (global_load_lds requirement) and pre-swizzles
// the per-lane GLOBAL source row (lane ^ 2*ks) -- both-sides-or-neither rule.
// LOGITS=false: split hi/lo C [M,N] row-major (+opt fp32 bias).
// LOGITS=true : logits[b,n] += sum_m w[m]*tanh(C[m,n]) (atomic).
template <bool LOGITS>
__global__ __launch_bounds__(512, 2) void mm8p(
    const u16* __restrict__ Ahp, const u16* __restrict__ Alp, long batchA, int ldA,
    const u16* __restrict__ Bhp, const u16* __restrict__ Blp, long batchB, int ldB,
    int N, int K, int gx, int gy,
    const float* __restrict__ bias,
    u16* __restrict__ Ch, u16* __restrict__ Cl, long batchC,
    const float* __restrict__ w, float* __restrict__ logits)
{
    __shared__ u16 lds[2][4][4][256 * 8];   // 128 KiB

    const int tid = threadIdx.x;
    // bijective XCD-chunked swizzle
    const int nwg = (int)gridDim.x;
    int bid = (int)blockIdx.x;
    {
        int q = nwg >> 3, r = nwg & 7, xcd = bid & 7, idx = bid >> 3;
        bid = (xcd < r ? xcd * (q + 1) : r * (q + 1) + (xcd - r) * q) + idx;
    }
    const int bpz = gx * gy;
    const int b    = bid / bpz;
    const int brem = bid - b * bpz;
    const int m0 = (brem / gx) * 256;
    const int n0 = (brem % gx) * 256;

    const u16* Ahb = Ahp + (long)b * batchA;
    const u16* Alb = Alp + (long)b * batchA;
    const u16* Bhb = Bhp + (long)b * batchB;
    const u16* Blb = Blp + (long)b * batchB;

    const int wave = tid >> 6, lane = tid & 63;
    const int quad = lane >> 4, l16 = lane & 15;
    const int l16x = l16 ^ (2 * quad);     // bank-rotation read slot
    const int wm = (wave >> 2) * 128;      // 2 wave-rows
    const int wn = (wave & 3) * 64;        // 4 wave-cols

    // staging role: wave w stages matrix (w>>1), rows [(w&1)*128, +128)
    const int smat  = wave >> 1;           // 0=Ah 1=Al 2=Bh 3=Bl
    const int srow0 = (wave & 1) * 128;
    const u16* srcp = smat == 0 ? Ahb : smat == 1 ? Alb : smat == 2 ? Bhb : Blb;
    const long sld  = (smat < 2) ? ldA : ldB;
    const int rowbase = (smat < 2) ? m0 : n0;
    const long sbase0 = (long)(rowbase + srow0);

    floatx4 acc[8][4] = {};

#define STAGE(buf_, kt_, j_) do {                                            \
        const int ks_ = (j_) >> 1, half_ = (j_) & 1;                         \
        const long grow_ = sbase0 + half_ * 64 + (lane ^ (2 * ks_));         \
        gload16(srcp + grow_ * sld + (long)(kt_) * 32 + ks_ * 8,             \
                &lds[buf_][smat][ks_][(srow0 + half_ * 64) * 8]);            \
    } while (0)

    // prologue: stage K-tile 0 into buf 0
#pragma unroll
    for (int j = 0; j < 8; ++j) STAGE(0, 0, j);
    asm volatile("s_waitcnt vmcnt(0)" ::: "memory");
    __builtin_amdgcn_s_barrier();

    const int NT = K >> 5;
    for (int t = 0; t < NT; ++t) {
        const int  cur = t & 1;
        const bool pf  = (t + 1 < NT);
        short8 bh[4], bl[4];
#pragma unroll
        for (int p = 0; p < 4; ++p) {
            if (p == 0) {
#pragma unroll
                for (int nt = 0; nt < 4; ++nt) {
                    const int bs = (wn + nt * 16 + l16x) * 8;
                    bh[nt] = *(const short8*)&lds[cur][2][quad][bs];
                    bl[nt] = *(const short8*)&lds[cur][3][quad][bs];
                }
            }
            const int as0 = (wm + p * 32 + l16x) * 8;
            const int as1 = as0 + 16 * 8;
            const short8 a0h = *(const short8*)&lds[cur][0][quad][as0];
            const short8 a0l = *(const short8*)&lds[cur][1][quad][as0];
            const short8 a1h = *(const short8*)&lds[cur][0][quad][as1];
            const short8 a1l = *(const short8*)&lds[cur][1][quad][as1];
            if (pf && p < 2) {   // issue next-tile stages early (phases 0,1)
                const int tb = cur ^ 1;
#pragma unroll
                for (int j = p * 4; j < p * 4 + 4; ++j) STAGE(tb, t + 1, j);
            }
            __builtin_amdgcn_s_barrier();
            __builtin_amdgcn_s_setprio(1);
#pragma unroll
            for (int nt = 0; nt < 4; ++nt) {
                floatx4 c0 = acc[2 * p][nt];
                c0 = __builtin_amdgcn_mfma_f32_16x16x32_bf16(a0h, bh[nt], c0, 0, 0, 0);
                c0 = __builtin_amdgcn_mfma_f32_16x16x32_bf16(a0h, bl[nt], c0, 0, 0, 0);
                c0 = __builtin_amdgcn_mfma_f32_16x16x32_bf16(a0l, bh[nt], c0, 0, 0, 0);
                acc[2 * p][nt] = c0;
                floatx4 c1 = acc[2 * p + 1][nt];
                c1 = __builtin_amdgcn_mfma_f32_16x16x32_bf16(a1h, bh[nt], c1, 0, 0, 0);
                c1 = __builtin_amdgcn_mfma_f32_16x16x32_bf16(a1h, bl[nt], c1, 0, 0, 0);
                c1 = __builtin_amdgcn_mfma_f32_16x16x32_bf16(a1l, bh[nt], c1, 0, 0, 0);
                acc[2 * p + 1][nt] = c1;
            }
            __builtin_amdgcn_s_setprio(0);
            // once per K-tile: publish next buffer (phases 2-3 of MFMA cover it)
            if (p == 3 && pf) asm volatile("s_waitcnt vmcnt(0)" ::: "memory");
            __builtin_amdgcn_s_barrier();
        }
    }
#undef STAGE

    if constexpr (!LOGITS) {
        u16* Chb = Ch + (long)b * batchC;
        u16* Clb = Cl + (long)b * batchC;
#pragma unroll
        for (int mt = 0; mt < 8; ++mt)
#pragma unroll
            for (int nt = 0; nt < 4; ++nt)
#pragma unroll
                for (int r = 0; r < 4; ++r) {
                    const int row = m0 + wm + mt * 16 + quad * 4 + r;
                    const int col = n0 + wn + nt * 16 + l16;
                    float x = acc[mt][nt][r];
                    if (bias) x += bias[(long)row * N + col];
                    const u16 h = f32_to_bf16(x);
                    Chb[(long)row * N + col] = h;
                    Clb[(long)row * N + col] = f32_to_bf16(x - bf16_to_f32(h));
                }
    } else {
        float cs[4] = {};
#pragma unroll
        for (int nt = 0; nt < 4; ++nt)
#pragma unroll
            for (int mt = 0; mt < 8; ++mt)
#pragma unroll
                for (int r = 0; r < 4; ++r) {
                    const int row = m0 + wm + mt * 16 + quad * 4 + r;
                    cs[nt] = fmaf(w[row], fast_tanh(acc[mt][nt][r]), cs[nt]);
                }
        float* red = (float*)&lds[0][0][0][0];   // 8 x 256 f32 (8 KB), safe post-loop
        const int r8 = (wave >> 2) * 4 + quad;
#pragma unroll
        for (int nt = 0; nt < 4; ++nt)
            red[r8 * 256 + wn + nt * 16 + l16] = cs[nt];
        __syncthreads();
        if (tid < 256) {
            float s = 0.f;
#pragma unroll
            for (int r = 0; r < 8; ++r) s += red[r * 256 + tid];
            atomicAdd(logits + (long)b * N + n0 + tid, s);
        }
    }
}

// ================= unified bf16x3 MFMA GEMM (128^2, kept for T/U) =================
// Same kslot-paged + XOR-rotated LDS layout as mm8p (register-staged writes).
template <bool LOGITS>
__global__ __launch_bounds__(256) void mm3(
    const u16* __restrict__ Ahp, const u16* __restrict__ Alp, long batchA, int ldA,
    const u16* __restrict__ Bhp, const u16* __restrict__ Blp, long batchB, int ldB,
    int N, int K,
    const float* __restrict__ bias,
    u16* __restrict__ Ch, u16* __restrict__ Cl, long batchC,
    const float* __restrict__ w, float* __restrict__ logits)
{
    __shared__ u16 Ah[4][128 * 8], Al[4][128 * 8], Bh[4][128 * 8], Bl[4][128 * 8];
    const int tid = threadIdx.x;
    const int b   = blockIdx.z;
    const int m0  = blockIdx.y * 128;
    const int n0  = blockIdx.x * 128;
    const u16* Ahb = Ahp + (long)b * batchA;
    const u16* Alb = Alp + (long)b * batchA;
    const u16* Bhb = Bhp + (long)b * batchB;
    const u16* Blb = Blp + (long)b * batchB;
    const int wave = tid >> 6, lane = tid & 63, quad = lane >> 4, l16 = lane & 15;
    const int l16x = l16 ^ (2 * quad);
    const int wm = (wave >> 1) * 64, wn = (wave & 1) * 64;
    floatx4 acc[4][4] = {};

    for (int k0 = 0; k0 < K; k0 += 32) {
#pragma unroll
        for (int i = 0; i < 2; ++i) {
            int c = i * 256 + tid;
            int row = (c & 63) + (c >> 8) * 64;   // 0..127
            int ks  = (c >> 6) & 3;               // kslot
            int slot = row ^ (2 * ks);
            long ga = (long)(m0 + row) * ldA + k0 + ks * 8;
            long gb = (long)(n0 + row) * ldB + k0 + ks * 8;
            *(short8*)&Ah[ks][slot * 8] = *(const short8*)&Ahb[ga];
            *(short8*)&Al[ks][slot * 8] = *(const short8*)&Alb[ga];
            *(short8*)&Bh[ks][slot * 8] = *(const short8*)&Bhb[gb];
            *(short8*)&Bl[ks][slot * 8] = *(const short8*)&Blb[gb];
        }
        __syncthreads();
        short8 ah[4], al[4], bh[4], bl[4];
#pragma unroll
        for (int t4 = 0; t4 < 4; ++t4) {
            const int as = (wm + t4 * 16 + l16x) * 8;
            ah[t4] = *(const short8*)&Ah[quad][as];
            al[t4] = *(const short8*)&Al[quad][as];
            const int bs = (wn + t4 * 16 + l16x) * 8;
            bh[t4] = *(const short8*)&Bh[quad][bs];
            bl[t4] = *(const short8*)&Bl[quad][bs];
        }
#pragma unroll
        for (int mt = 0; mt < 4; ++mt)
#pragma unroll
            for (int nt = 0; nt < 4; ++nt) {
                floatx4 a0 = acc[mt][nt];
                a0 = __builtin_amdgcn_mfma_f32_16x16x32_bf16(ah[mt], bh[nt], a0, 0, 0, 0);
                a0 = __builtin_amdgcn_mfma_f32_16x16x32_bf16(ah[mt], bl[nt], a0, 0, 0, 0);
                a0 = __builtin_amdgcn_mfma_f32_16x16x32_bf16(al[mt], bh[nt], a0, 0, 0, 0);
                acc[mt][nt] = a0;
            }
        __syncthreads();
    }

    if constexpr (!LOGITS) {
        u16* Chb = Ch + (long)b * batchC;
        u16* Clb = Cl + (long)b * batchC;
#pragma unroll
        for (int mt = 0; mt < 4; ++mt)
#pragma unroll
            for (int nt = 0; nt < 4; ++nt)
#pragma unroll
                for (int r = 0; r < 4; ++r) {
                    int row = m0 + wm + mt * 16 + quad * 4 + r;
                    int col = n0 + wn + nt * 16 + l16;
                    float x = acc[mt][nt][r];
                    if (bias) x += bias[(long)row * N + col];
                    u16 h = f32_to_bf16(x);
                    u16 l = f32_to_bf16(x - bf16_to_f32(h));
                    Chb[(long)row * N + col] = h;
                    Clb[(long)row * N + col] = l;
                }
    } else {
        float cs[4] = {};
#pragma unroll
        for (int nt = 0; nt < 4; ++nt)
#pragma unroll
            for (int mt = 0; mt < 4; ++mt)
#pragma unroll
                for (int r = 0; r < 4; ++r) {
                    int row = m0 + wm + mt * 16 + quad * 4 + r;
                    cs[nt] = fmaf(w[row], fast_tanh(acc[mt][nt][r]), cs[nt]);
                }
        float* red = (float*)&Ah[0][0];   // 8 x 128 floats (4 KB), safe post-loop
        const int r8 = (wave >> 1) * 4 + quad;
#pragma unroll
        for (int nt = 0; nt < 4; ++nt)
            red[r8 * 128 + wn + nt * 16 + l16] = cs[nt];
        __syncthreads();
        if (tid < 128) {
            float s = 0.f;
#pragma unroll
            for (int r = 0; r < 8; ++r) s += red[r * 128 + tid];
            atomicAdd(logits + (long)b * N + n0 + tid, s);
        }
    }
}

// ---------------- conversions ----------------
// elementwise split; grid*1024 must equal element count
__global__ __launch_bounds__(256) void split_kernel(
    const float* __restrict__ X, u16* __restrict__ Xh, u16* __restrict__ Xl)
{
    long i0 = ((long)blockIdx.x * 256 + threadIdx.x) * 4;
    float4 v = *(const float4*)(X + i0);
    float xs[4] = {v.x, v.y, v.z, v.w};
    u16 h[4], l[4];
#pragma unroll
    for (int i = 0; i < 4; ++i) {
        h[i] = f32_to_bf16(xs[i]);
        l[i] = f32_to_bf16(xs[i] - bf16_to_f32(h[i]));
    }
    *(ushort4*)(Xh + i0) = *(ushort4*)h;
    *(ushort4*)(Xl + i0) = *(ushort4*)l;
}

// transpose + split: src [b,R,C] -> dst [b,C,R]; grid (R/64, C/64, batch)
__global__ __launch_bounds__(256) void tsplit_kernel(
    const float* __restrict__ src, u16* __restrict__ dh, u16* __restrict__ dl,
    int R, int C)
{
    __shared__ float tile[64][65];
    const int b = blockIdx.z;
    const int r0 = blockIdx.x * 64, c0 = blockIdx.y * 64;
    const float* S = src + (long)b * R * C;
    const int t = threadIdx.x;
    const int lr = t >> 2, lc0 = (t & 3) * 16;
#pragma unroll
    for (int i = 0; i < 4; ++i)
        *(float4*)&tile[lr][lc0 + i * 4] =
            *(const float4*)(S + (long)(r0 + lr) * C + c0 + lc0 + i * 4);
    __syncthreads();
    u16 hbuf[16], lbuf[16];
#pragma unroll
    for (int i = 0; i < 16; ++i) {
        float x = tile[lc0 + i][lr];
        u16 hi = f32_to_bf16(x);
        hbuf[i] = hi;
        lbuf[i] = f32_to_bf16(x - bf16_to_f32(hi));
    }
    long o = (long)b * R * C + (long)(c0 + lr) * R + r0 + lc0;
    *(short8*)(dh + o)     = *(short8*)&hbuf[0];
    *(short8*)(dh + o + 8) = *(short8*)&hbuf[8];
    *(short8*)(dl + o)     = *(short8*)&lbuf[0];
    *(short8*)(dl + o + 8) = *(short8*)&lbuf[8];
}

// ---------------- fp32 GEMM (fallback tier only) ----------------
template <bool LOGITS>
__global__ __launch_bounds__(256) void gemm_core(
    const float* __restrict__ A, const float* __restrict__ Bm, float* __restrict__ C,
    const float* __restrict__ bias,
    int M, int N, int K,
    int sAm, int sAk, long batchA,
    int sBk, int sBn, long batchB,
    long batchC,
    const float* __restrict__ w, float* __restrict__ logits)
{
    __shared__ float As[BK][LDT];
    __shared__ float Bs[BK][LDT];
    const int tid = threadIdx.x;
    const int b   = blockIdx.z;
    const int m0  = blockIdx.y * BM;
    const int n0  = blockIdx.x * BN;
    const float* Ab = A  + (long)b * batchA;
    const float* Bb = Bm + (long)b * batchB;
    const int tm = tid >> 4, tn = tid & 15;
    float acc[8][8] = {};

    for (int k0 = 0; k0 < K; k0 += BK) {
        if (sAk == 1) {
#pragma unroll
            for (int i = 0; i < 2; ++i) {
                int idx = tid + i * 256;
                int m = idx >> 2, kg = (idx & 3) * 4;
                float4 v = *(const float4*)(Ab + (long)(m0 + m) * sAm + k0 + kg);
                As[kg+0][m] = v.x; As[kg+1][m] = v.y; As[kg+2][m] = v.z; As[kg+3][m] = v.w;
            }
        } else {
#pragma unroll
            for (int i = 0; i < 2; ++i) {
                int idx = tid + i * 256;
                int k = idx >> 5, mg = (idx & 31) * 4;
                float4 v = *(const float4*)(Ab + (long)(k0 + k) * sAk + m0 + mg);
                *(float4*)&As[k][mg] = v;
            }
        }
        if (sBn == 1) {
#pragma unroll
            for (int i = 0; i < 2; ++i) {
                int idx = tid + i * 256;
                int k = idx >> 5, ng = (idx & 31) * 4;
                float4 v = *(const float4*)(Bb + (long)(k0 + k) * sBk + n0 + ng);
                *(float4*)&Bs[k][ng] = v;
            }
        } else {
#pragma unroll
            for (int i = 0; i < 2; ++i) {
                int idx = tid + i * 256;
                int n = idx >> 2, kg = (idx & 3) * 4;
                float4 v = *(const float4*)(Bb + (long)(n0 + n) * sBn + k0 + kg);
                Bs[kg+0][n] = v.x; Bs[kg+1][n] = v.y; Bs[kg+2][n] = v.z; Bs[kg+3][n] = v.w;
            }
        }
        __syncthreads();
#pragma unroll
        for (int kk = 0; kk < BK; ++kk) {
            float a[8], bv[8];
            *(float4*)&a[0]  = *(const float4*)&As[kk][tm * 4];
            *(float4*)&a[4]  = *(const float4*)&As[kk][64 + tm * 4];
            *(float4*)&bv[0] = *(const float4*)&Bs[kk][tn * 4];
            *(float4*)&bv[4] = *(const float4*)&Bs[kk][64 + tn * 4];
#pragma unroll
            for (int i = 0; i < 8; ++i)
#pragma unroll
                for (int j = 0; j < 8; ++j)
                    acc[i][j] = fmaf(a[i], bv[j], acc[i][j]);
        }
        __syncthreads();
    }

    if constexpr (!LOGITS) {
        float* Cb = C + (long)b * batchC;
#pragma unroll
        for (int i = 0; i < 8; ++i) {
            int row = m0 + (i >> 2) * 64 + tm * 4 + (i & 3);
            float* crow = Cb + (long)row * N + n0;
            float4 o0 = {acc[i][0], acc[i][1], acc[i][2], acc[i][3]};
            float4 o1 = {acc[i][4], acc[i][5], acc[i][6], acc[i][7]};
            if (bias) {
                const float* brow = bias + (long)row * N + n0;
                float4 b0 = *(const float4*)(brow + tn * 4);
                float4 b1 = *(const float4*)(brow + 64 + tn * 4);
                o0.x += b0.x; o0.y += b0.y; o0.z += b0.z; o0.w += b0.w;
                o1.x += b1.x; o1.y += b1.y; o1.z += b1.z; o1.w += b1.w;
            }
            *(float4*)(crow + tn * 4) = o0;
            *(float4*)(crow + 64 + tn * 4) = o1;
        }
    } else {
        float wv[8];
#pragma unroll
        for (int i = 0; i < 8; ++i) wv[i] = w[m0 + (i >> 2) * 64 + tm * 4 + (i & 3)];
        float cs[8];
#pragma unroll
        for (int j = 0; j < 8; ++j) {
            float s = 0.f;
#pragma unroll
            for (int i = 0; i < 8; ++i) s = fmaf(wv[i], fast_tanh(acc[i][j]), s);
            cs[j] = s;
        }
        __syncthreads();
        *(float4*)&As[tm][tn * 4]      = *(float4*)&cs[0];
        *(float4*)&As[tm][64 + tn * 4] = *(float4*)&cs[4];
        __syncthreads();
        if (tid < 128) {
            float s = 0.f;
#pragma unroll
            for (int r = 0; r < 16; ++r) s += As[r][tid];
            atomicAdd(logits + (long)b * N + n0 + tid, s);
        }
    }
}

// ---------------- small kernels ----------------
__global__ __launch_bounds__(256) void softmax_kernel(
    const float* __restrict__ lv, const float* __restrict__ lq, float* __restrict__ out)
{
    const int b = blockIdx.x;
    const int which = blockIdx.y;
    const float* x = (which == 0 ? lv : lq) + (long)b * 2048;
    float* o = out + (long)which * (Bn * 2048) + (long)b * 2048;
    const int tid = threadIdx.x;
    __shared__ float sm[4], ss[4];

    float m = -3.4e38f;
    for (int i = tid; i < 2048; i += 256) m = fmaxf(m, x[i]);
    for (int off = 32; off > 0; off >>= 1) m = fmaxf(m, __shfl_down(m, off));
    if ((tid & 63) == 0) sm[tid >> 6] = m;
    __syncthreads();
    m = fmaxf(fmaxf(sm[0], sm[1]), fmaxf(sm[2], sm[3]));

    float s = 0.f;
    for (int i = tid; i < 2048; i += 256) s += expf(x[i] - m);
    for (int off = 32; off > 0; off >>= 1) s += __shfl_down(s, off);
    if ((tid & 63) == 0) ss[tid >> 6] = s;
    __syncthreads();
    s = ss[0] + ss[1] + ss[2] + ss[3];
    float inv = 1.0f / s;
    for (int i = tid; i < 2048; i += 256) o[i] = expf(x[i] - m) * inv;
}

__global__ __launch_bounds__(256) void vout_kernel(
    const float* __restrict__ V, const float* __restrict__ av, float* __restrict__ vout)
{
    const int wave = threadIdx.x >> 6, lane = threadIdx.x & 63;
    const long idx = (long)blockIdx.x * 4 + wave;
    const int b = (int)(idx >> 10);
    const int h = (int)(idx & 1023);
    const float* vp = V + ((long)b * Hd + h) * NVn;
    const float* ap = av + (long)b * NVn;
    float s = 0.f;
    for (int i = lane; i < NVn; i += 64) s = fmaf(ap[i], vp[i], s);
    for (int off = 32; off > 0; off >>= 1) s += __shfl_down(s, off);
    if (lane == 0) vout[idx] = s;
}

__global__ __launch_bounds__(256) void qout_kernel(
    const float* __restrict__ Q, const float* __restrict__ aq, float* __restrict__ qout)
{
    const int h  = blockIdx.x * 256 + threadIdx.x;
    const int b  = blockIdx.z;
    const int q0 = blockIdx.y * 256;
    const float* qp = Q + (long)b * NQn * Hd;
    const float* ap = aq + (long)b * NQn + q0;
    float s = 0.f;
    for (int q = 0; q < 256; ++q) s = fmaf(ap[q], qp[(long)(q0 + q) * Hd + h], s);
    atomicAdd(qout + (long)b * Hd + h, s);
}

extern "C" void kernel_launch(void* const* d_in, const int* in_sizes, int n_in,
                              void* d_out, int out_size, void* d_ws, size_t ws_size,
                              hipStream_t stream) {
    const float* V    = (const float*)d_in[0];
    const float* Q    = (const float*)d_in[1];
    const float* W_b  = (const float*)d_in[2];
    const float* W_v  = (const float*)d_in[3];
    const float* W_q  = (const float*)d_in[4];
    const float* w_hv = (const float*)d_in[5];
    const float* w_hq = (const float*)d_in[6];
    float* out = (float*)d_out;
    dim3 blk(256);

    const long BIG  = (long)Bn * Hd * NVn;   // 33.55M (one big matrix, one half)
    const long GEL  = (long)Bn * Hd * Hd;    // 16.78M
    const long TEL  = (long)Bn * COn * Hd;   // 8.39M
    const long WQE  = (long)COn * Hd;        // 0.52M
    const long WBE  = (long)Hd * Hd;         // 1.05M

    // u16 layout
    u16* ws16 = (u16*)d_ws;
    u16* R1h  = ws16;            u16* R1l  = R1h + BIG;      // 134 MB shared region
    u16* Gh   = R1l + BIG;       u16* Gl   = Gh + GEL;       // 67 MB
    u16* Th   = Gl + GEL;        u16* Tl   = Th + TEL;       // 33.5 MB
    u16* Uh   = Gh;              u16* Ul   = Gh + TEL;       // U aliases dead G
    u16* Wqh  = Tl + TEL;        u16* Wql  = Wqh + WQE;
    u16* Wvh  = Wql + WQE;       u16* Wvl  = Wvh + WQE;
    u16* Wbh  = Wvl + WQE;       u16* Wbl  = Wbh + WBE;
    u16* WbTh = Wbl + WBE;       u16* WbTl = WbTh + WBE;
    float* lv = (float*)(WbTl + WBE);
    float* lq = lv + Bn * NVn;
    const size_t need = (size_t)((u16*)(lq + Bn * NQn) - ws16) * 2;

    float* vout_p = out + 2 * Bn * NVn;
    float* qout_p = vout_p + Bn * Hd;

    if (ws_size >= need) {
        hipMemsetAsync(lv, 0, (size_t)(Bn * NVn + Bn * NQn) * sizeof(float), stream);
        hipMemsetAsync(qout_p, 0, (size_t)Bn * Hd * sizeof(float), stream);

        // weight splits
        split_kernel<<<dim3((unsigned)(WQE / 1024)), blk, 0, stream>>>(W_q, Wqh, Wql);
        split_kernel<<<dim3((unsigned)(WQE / 1024)), blk, 0, stream>>>(W_v, Wvh, Wvl);
        split_kernel<<<dim3((unsigned)(WBE / 1024)), blk, 0, stream>>>(W_b, Wbh, Wbl);
        tsplit_kernel<<<dim3(Hd / 64, Hd / 64, 1), blk, 0, stream>>>(W_b, WbTh, WbTl, Hd, Hd);

        // ---- chain Q ----
        tsplit_kernel<<<dim3(NQn / 64, Hd / 64, Bn), blk, 0, stream>>>(Q, R1h, R1l, NQn, Hd);
        // G_Q = QT QT^T  [Hd,Hd]  (256^2 phase-split kernel)
        mm8p<false><<<dim3((Hd / 256) * (Hd / 256) * Bn), dim3(512), 0, stream>>>(
            R1h, R1l, (long)Hd * NQn, NQn,  R1h, R1l, (long)Hd * NQn, NQn,
            Hd, NQn, Hd / 256, Hd / 256,
            nullptr, Gh, Gl, (long)Hd * Hd, nullptr, nullptr);
        // T = W_q @ G (G symmetric: B = G k-contig)
        mm3<false><<<dim3(Hd / 128, COn / 128, Bn), blk, 0, stream>>>(
            Wqh, Wql, 0L, Hd,  Gh, Gl, (long)Hd * Hd, Hd,
            Hd, Hd, nullptr, Th, Tl, (long)COn * Hd, nullptr, nullptr);
        // U = T @ W_b + W_v  (B = W_b^T pre-transposed)
        mm3<false><<<dim3(Hd / 128, COn / 128, Bn), blk, 0, stream>>>(
            Th, Tl, (long)COn * Hd, Hd,  WbTh, WbTl, 0L, Hd,
            Hd, Hd, W_v, Uh, Ul, (long)COn * Hd, nullptr, nullptr);
        // VT for logits B operand (QT dead)
        tsplit_kernel<<<dim3(Hd / 64, NVn / 64, Bn), blk, 0, stream>>>(V, R1h, R1l, Hd, NVn);
        // logits_v += w_hv . tanh(U @ V)
        mm8p<true><<<dim3((NVn / 256) * (COn / 256) * Bn), dim3(512), 0, stream>>>(
            Uh, Ul, (long)COn * Hd, Hd,  R1h, R1l, (long)NVn * Hd, Hd,
            NVn, Hd, NVn / 256, COn / 256,
            nullptr, nullptr, nullptr, 0L, w_hv, lv);

        // ---- chain V ----
        split_kernel<<<dim3((unsigned)(BIG / 1024)), blk, 0, stream>>>(V, R1h, R1l);
        // G_V = V V^T
        mm8p<false><<<dim3((Hd / 256) * (Hd / 256) * Bn), dim3(512), 0, stream>>>(
            R1h, R1l, (long)Hd * NVn, NVn,  R1h, R1l, (long)Hd * NVn, NVn,
            Hd, NVn, Hd / 256, Hd / 256,
            nullptr, Gh, Gl, (long)Hd * Hd, nullptr, nullptr);
        // T = W_v @ G
        mm3<false><<<dim3(Hd / 128, COn / 128, Bn), blk, 0, stream>>>(
            Wvh, Wvl, 0L, Hd,  Gh, Gl, (long)Hd * Hd, Hd,
            Hd, Hd, nullptr, Th, Tl, (long)COn * Hd, nullptr, nullptr);
        // U = T @ W_b^T + W_q  (B = W_b row-major already [n,k])
        mm3<false><<<dim3(Hd / 128, COn / 128, Bn), blk, 0, stream>>>(
            Th, Tl, (long)COn * Hd, Hd,  Wbh, Wbl, 0L, Hd,
            Hd, Hd, W_q, Uh, Ul, (long)COn * Hd, nullptr, nullptr);
        // Q split (elementwise) for logits B operand (Vsplit dead)
        split_kernel<<<dim3((unsigned)(BIG / 1024)), blk, 0, stream>>>(Q, R1h, R1l);
        // logits_q += w_hq . tanh(U @ Q^T)
        mm8p<true><<<dim3((NQn / 256) * (COn / 256) * Bn), dim3(512), 0, stream>>>(
            Uh, Ul, (long)COn * Hd, Hd,  R1h, R1l, (long)NQn * Hd, Hd,
            NQn, Hd, NQn / 256, COn / 256,
            nullptr, nullptr, nullptr, 0L, w_hq, lq);

        softmax_kernel<<<dim3(Bn, 2), blk, 0, stream>>>(lv, lq, out);
        vout_kernel<<<dim3(Bn * Hd / 4), blk, 0, stream>>>(V, out, vout_p);
        qout_kernel<<<dim3(Hd / 256, NQn / 256, Bn), blk, 0, stream>>>(Q, out + Bn * NVn, qout_p);
        return;
    }

    // ---------------- fp32 fallback tier ----------------
    float* ws = (float*)d_ws;
    float* g  = ws;
    float* t  = g + GEL;
    float* u  = t + TEL;
    float* flv = u + TEL;
    float* flq = flv + Bn * NVn;

    hipMemsetAsync(flv, 0, (size_t)(Bn * NVn + Bn * NQn) * sizeof(float), stream);
    hipMemsetAsync(qout_p, 0, (size_t)Bn * Hd * sizeof(float), stream);

    gemm_core<false><<<dim3(Hd/BN, Hd/BM, Bn), blk, 0, stream>>>(Q, Q, g, nullptr,
        Hd, Hd, NQn, 1, Hd, (long)NQn*Hd, Hd, 1, (long)NQn*Hd, (long)Hd*Hd, nullptr, nullptr);
    gemm_core<false><<<dim3(Hd/BN, COn/BM, Bn), blk, 0, stream>>>(W_q, g, t, nullptr,
        COn, Hd, Hd, Hd, 1, 0L, Hd, 1, (long)Hd*Hd, (long)COn*Hd, nullptr, nullptr);
    gemm_core<false><<<dim3(Hd/BN, COn/BM, Bn), blk, 0, stream>>>(t, W_b, u, W_v,
        COn, Hd, Hd, Hd, 1, (long)COn*Hd, Hd, 1, 0L, (long)COn*Hd, nullptr, nullptr);
    gemm_core<true><<<dim3(NVn/BN, COn/BM, Bn), blk, 0, stream>>>(
        u, V, nullptr, nullptr, COn, NVn, Hd,
        Hd, 1, (long)COn*Hd, NVn, 1, (long)Hd*NVn, 0L, w_hv, flv);
    gemm_core<false><<<dim3(Hd/BN, Hd/BM, Bn), blk, 0, stream>>>(V, V, g, nullptr,
        Hd, Hd, NVn, NVn, 1, (long)Hd*NVn, 1, NVn, (long)Hd*NVn, (long)Hd*Hd, nullptr, nullptr);
    gemm_core<false><<<dim3(Hd/BN, COn/BM, Bn), blk, 0, stream>>>(W_v, g, t, nullptr,
        COn, Hd, Hd, Hd, 1, 0L, Hd, 1, (long)Hd*Hd, (long)COn*Hd, nullptr, nullptr);
    gemm_core<false><<<dim3(Hd/BN, COn/BM, Bn), blk, 0, stream>>>(t, W_b, u, W_q,
        COn, Hd, Hd, Hd, 1, (long)COn*Hd, 1, Hd, 0L, (long)COn*Hd, nullptr, nullptr);
    gemm_core<true><<<dim3(NQn/BN, COn/BM, Bn), blk, 0, stream>>>(
        u, Q, nullptr, nullptr, COn, NQn, Hd,
        Hd, 1, (long)COn*Hd, 1, Hd, (long)NQn*Hd, 0L, w_hq, flq);

    softmax_kernel<<<dim3(Bn, 2), blk, 0, stream>>>(flv, flq, out);
    vout_kernel<<<dim3(Bn * Hd / 4), blk, 0, stream>>>(V, out, vout_p);
    qout_kernel<<<dim3(Hd / 256, NQn / 256, Bn), blk, 0, stream>>>(Q, out + Bn * NVn, qout_p);
}

// Round 4
// 1256.808 us; speedup vs baseline: 1.3521x; 1.3521x over previous
//
#include <hip/hip_runtime.h>
#include <math.h>

#define Bn  16
#define Hd  1024
#define COn 512
#define NVn 2048
#define NQn 2048

#define BM 128
#define BN 128
#define BK 16
#define LDT 132

typedef unsigned short u16;
typedef __attribute__((ext_vector_type(8))) short short8;
typedef __attribute__((ext_vector_type(4))) float floatx4;

__device__ __forceinline__ float fast_tanh(float x) {
    float ax = fabsf(x);
    float e  = __expf(2.0f * ax);
    float t  = 1.0f - 2.0f / (e + 1.0f);
    return copysignf(t, x);
}

__device__ __forceinline__ u16 f32_to_bf16(float x) {
    unsigned u = __float_as_uint(x);
    unsigned r = (u + 0x7fffu + ((u >> 16) & 1u)) >> 16;   // RNE, finite inputs
    return (u16)r;
}
__device__ __forceinline__ float bf16_to_f32(u16 h) {
    return __uint_as_float(((unsigned)h) << 16);
}

// async global->LDS, 16B per lane. LDS dest is wave-uniform base + lane*16.
__device__ __forceinline__ void gload16(const u16* g, u16* l) {
    __builtin_amdgcn_global_load_lds(
        (__attribute__((address_space(1))) void*)(g),
        (__attribute__((address_space(3))) void*)(l), 16, 0, 0);
}

// ================= 256x256 8-wave phase-split bf16x3 GEMM =================
// C = A*B (+bias): A [M,K] k-contig hi/lo, B TRANSPOSED [N,K] k-contig hi/lo.
// grid = gx*gy*Bn (1D, XCD-swizzled), block = 512.  M = gy*256, N = gx*256,
// K mult of 32 (>=64).
// LDS: row-major [256 rows][32 u16] per matrix (64B rows, coalesced staging:
// 4 lanes = one 64B line). Bank fix: k-slot ROTATED WITHIN each row's 64B:
// unit u holds global kslot u ^ ((row>>1)&3). Global side permutes only
// inside the 64B line (coalescing preserved); reads use per-lane constant
// xsl -> quarter-wave spreads over all 8 bank-groups (2-way = free).
// Sync: ONE vmcnt(0)+barrier per K-tile (double-buffer hand-off only);
// no intra-tile barriers -> waves drift, MFMA overlaps LDS across waves.
// LOGITS=false: split hi/lo C [M,N] row-major (+opt fp32 bias).
// LOGITS=true : logits[b,n] += sum_m w[m]*tanh(C[m,n]) (atomic).
template <bool LOGITS>
__global__ __launch_bounds__(512, 2) void mm8p(
    const u16* __restrict__ Ahp, const u16* __restrict__ Alp, long batchA, int ldA,
    const u16* __restrict__ Bhp, const u16* __restrict__ Blp, long batchB, int ldB,
    int N, int K, int gx, int gy,
    const float* __restrict__ bias,
    u16* __restrict__ Ch, u16* __restrict__ Cl, long batchC,
    const float* __restrict__ w, float* __restrict__ logits)
{
    __shared__ u16 lds[2][4][256 * 32];   // 128 KiB: [buf][Ah,Al,Bh,Bl][row][k]

    const int tid = threadIdx.x;
    // bijective XCD-chunked swizzle
    const int nwg = (int)gridDim.x;
    int bid = (int)blockIdx.x;
    {
        int q = nwg >> 3, r = nwg & 7, xcd = bid & 7, idx = bid >> 3;
        bid = (xcd < r ? xcd * (q + 1) : r * (q + 1) + (xcd - r) * q) + idx;
    }
    const int bpz = gx * gy;
    const int b    = bid / bpz;
    const int brem = bid - b * bpz;
    const int m0 = (brem / gx) * 256;
    const int n0 = (brem % gx) * 256;

    const u16* Ahb = Ahp + (long)b * batchA;
    const u16* Alb = Alp + (long)b * batchA;
    const u16* Bhb = Bhp + (long)b * batchB;
    const u16* Blb = Blp + (long)b * batchB;

    const int wave = tid >> 6, lane = tid & 63;
    const int quad = lane >> 4, l16 = lane & 15;
    const int xsl = (quad ^ ((l16 >> 1) & 3)) * 8;   // in-row rotated k-slot (u16 units)
    const int wm = (wave >> 2) * 128;      // 2 wave-rows
    const int wn = (wave & 3) * 64;        // 4 wave-cols

    // staging role: wave w stages matrix (w>>1), rows [(w&1)*128, +128)
    const int smat  = wave >> 1;           // 0=Ah 1=Al 2=Bh 3=Bl
    const int srow0 = (wave & 1) * 128;
    const int srl   = lane >> 2;           // row within 16-row chunk
    const int kx    = ((lane & 3) ^ ((lane >> 3) & 3)) * 8;  // rotated source k-slot
    const u16* srcp = smat == 0 ? Ahb : smat == 1 ? Alb : smat == 2 ? Bhb : Blb;
    const long sld  = (smat < 2) ? ldA : ldB;
    const int rowbase = (smat < 2) ? m0 : n0;
    const u16* sp = srcp + (long)(rowbase + srow0 + srl) * sld + kx;

    floatx4 acc[8][4] = {};

    // prologue: stage K-tile 0 into buf 0
#pragma unroll
    for (int j = 0; j < 8; ++j)
        gload16(sp + (long)j * 16 * sld, &lds[0][smat][(srow0 + j * 16) * 32]);
    asm volatile("s_waitcnt vmcnt(0)" ::: "memory");
    __builtin_amdgcn_s_barrier();

    const int NT = K >> 5;
    for (int t = 0; t < NT; ++t) {
        const int  cur = t & 1;
        const bool pf  = (t + 1 < NT);
        const long k0n = (long)(t + 1) * 32;
        const u16* Ah_ = &lds[cur][0][0];
        const u16* Al_ = &lds[cur][1][0];
        const u16* Bh_ = &lds[cur][2][0];
        const u16* Bl_ = &lds[cur][3][0];

        short8 bh[4], bl[4];
#pragma unroll
        for (int nt = 0; nt < 4; ++nt) {
            const int bs = (wn + nt * 16 + l16) * 32 + xsl;
            bh[nt] = *(const short8*)&Bh_[bs];
            bl[nt] = *(const short8*)&Bl_[bs];
        }
        if (pf) {   // issue next-tile stages early; whole tile of MFMA covers them
            u16* dst = &lds[cur ^ 1][smat][srow0 * 32];
#pragma unroll
            for (int j = 0; j < 8; ++j)
                gload16(sp + (long)j * 16 * sld + k0n, dst + j * 16 * 32);
        }
#pragma unroll
        for (int p = 0; p < 4; ++p) {
            const int as0 = (wm + p * 32 + l16) * 32 + xsl;
            const int as1 = as0 + 16 * 32;
            const short8 a0h = *(const short8*)&Ah_[as0];
            const short8 a0l = *(const short8*)&Al_[as0];
            const short8 a1h = *(const short8*)&Ah_[as1];
            const short8 a1l = *(const short8*)&Al_[as1];
            __builtin_amdgcn_s_setprio(1);
#pragma unroll
            for (int nt = 0; nt < 4; ++nt) {
                floatx4 c0 = acc[2 * p][nt];
                c0 = __builtin_amdgcn_mfma_f32_16x16x32_bf16(a0h, bh[nt], c0, 0, 0, 0);
                c0 = __builtin_amdgcn_mfma_f32_16x16x32_bf16(a0h, bl[nt], c0, 0, 0, 0);
                c0 = __builtin_amdgcn_mfma_f32_16x16x32_bf16(a0l, bh[nt], c0, 0, 0, 0);
                acc[2 * p][nt] = c0;
                floatx4 c1 = acc[2 * p + 1][nt];
                c1 = __builtin_amdgcn_mfma_f32_16x16x32_bf16(a1h, bh[nt], c1, 0, 0, 0);
                c1 = __builtin_amdgcn_mfma_f32_16x16x32_bf16(a1h, bl[nt], c1, 0, 0, 0);
                c1 = __builtin_amdgcn_mfma_f32_16x16x32_bf16(a1l, bh[nt], c1, 0, 0, 0);
                acc[2 * p + 1][nt] = c1;
            }
            __builtin_amdgcn_s_setprio(0);
        }
        // publish next buffer: all ds_reads of buf[cur] retired (MFMA data deps),
        // all stage writes to buf[cur^1] landed (vmcnt 0).
        if (pf) asm volatile("s_waitcnt vmcnt(0)" ::: "memory");
        __builtin_amdgcn_s_barrier();
    }

    if constexpr (!LOGITS) {
        u16* Chb = Ch + (long)b * batchC;
        u16* Clb = Cl + (long)b * batchC;
#pragma unroll
        for (int mt = 0; mt < 8; ++mt)
#pragma unroll
            for (int nt = 0; nt < 4; ++nt)
#pragma unroll
                for (int r = 0; r < 4; ++r) {
                    const int row = m0 + wm + mt * 16 + quad * 4 + r;
                    const int col = n0 + wn + nt * 16 + l16;
                    float x = acc[mt][nt][r];
                    if (bias) x += bias[(long)row * N + col];
                    const u16 h = f32_to_bf16(x);
                    Chb[(long)row * N + col] = h;
                    Clb[(long)row * N + col] = f32_to_bf16(x - bf16_to_f32(h));
                }
    } else {
        float cs[4] = {};
#pragma unroll
        for (int nt = 0; nt < 4; ++nt)
#pragma unroll
            for (int mt = 0; mt < 8; ++mt)
#pragma unroll
                for (int r = 0; r < 4; ++r) {
                    const int row = m0 + wm + mt * 16 + quad * 4 + r;
                    cs[nt] = fmaf(w[row], fast_tanh(acc[mt][nt][r]), cs[nt]);
                }
        float* red = (float*)&lds[0][0][0];   // 8 x 256 f32 (8 KB), safe post-loop
        const int r8 = (wave >> 2) * 4 + quad;
#pragma unroll
        for (int nt = 0; nt < 4; ++nt)
            red[r8 * 256 + wn + nt * 16 + l16] = cs[nt];
        __syncthreads();
        if (tid < 256) {
            float s = 0.f;
#pragma unroll
            for (int r = 0; r < 8; ++r) s += red[r * 256 + tid];
            atomicAdd(logits + (long)b * N + n0 + tid, s);
        }
    }
}

// ================= unified bf16x3 MFMA GEMM (128^2, kept for T/U) =================
// Round-0 global pattern (4 lanes = one 64B line) + in-row rotated k-slot.
template <bool LOGITS>
__global__ __launch_bounds__(256) void mm3(
    const u16* __restrict__ Ahp, const u16* __restrict__ Alp, long batchA, int ldA,
    const u16* __restrict__ Bhp, const u16* __restrict__ Blp, long batchB, int ldB,
    int N, int K,
    const float* __restrict__ bias,
    u16* __restrict__ Ch, u16* __restrict__ Cl, long batchC,
    const float* __restrict__ w, float* __restrict__ logits)
{
    __shared__ u16 Ah[128 * 32], Al[128 * 32], Bh[128 * 32], Bl[128 * 32];
    const int tid = threadIdx.x;
    const int b   = blockIdx.z;
    const int m0  = blockIdx.y * 128;
    const int n0  = blockIdx.x * 128;
    const u16* Ahb = Ahp + (long)b * batchA;
    const u16* Alb = Alp + (long)b * batchA;
    const u16* Bhb = Bhp + (long)b * batchB;
    const u16* Blb = Blp + (long)b * batchB;
    const int wave = tid >> 6, lane = tid & 63, quad = lane >> 4, l16 = lane & 15;
    const int xsl = (quad ^ ((l16 >> 1) & 3)) * 8;
    const int wm = (wave >> 1) * 64, wn = (wave & 1) * 64;
    floatx4 acc[4][4] = {};

    for (int k0 = 0; k0 < K; k0 += 32) {
#pragma unroll
        for (int i = 0; i < 2; ++i) {
            int c = i * 256 + tid;
            int row = c >> 2, u = c & 3;
            int g = u ^ ((row >> 1) & 3);         // rotated source k-slot
            long ga = (long)(m0 + row) * ldA + k0 + g * 8;
            long gb = (long)(n0 + row) * ldB + k0 + g * 8;
            *(short8*)&Ah[row * 32 + u * 8] = *(const short8*)&Ahb[ga];
            *(short8*)&Al[row * 32 + u * 8] = *(const short8*)&Alb[ga];
            *(short8*)&Bh[row * 32 + u * 8] = *(const short8*)&Bhb[gb];
            *(short8*)&Bl[row * 32 + u * 8] = *(const short8*)&Blb[gb];
        }
        __syncthreads();
        short8 ah[4], al[4], bh[4], bl[4];
#pragma unroll
        for (int t4 = 0; t4 < 4; ++t4) {
            const int as = (wm + t4 * 16 + l16) * 32 + xsl;
            ah[t4] = *(const short8*)&Ah[as];
            al[t4] = *(const short8*)&Al[as];
            const int bs = (wn + t4 * 16 + l16) * 32 + xsl;
            bh[t4] = *(const short8*)&Bh[bs];
            bl[t4] = *(const short8*)&Bl[bs];
        }
#pragma unroll
        for (int mt = 0; mt < 4; ++mt)
#pragma unroll
            for (int nt = 0; nt < 4; ++nt) {
                floatx4 a0 = acc[mt][nt];
                a0 = __builtin_amdgcn_mfma_f32_16x16x32_bf16(ah[mt], bh[nt], a0, 0, 0, 0);
                a0 = __builtin_amdgcn_mfma_f32_16x16x32_bf16(ah[mt], bl[nt], a0, 0, 0, 0);
                a0 = __builtin_amdgcn_mfma_f32_16x16x32_bf16(al[mt], bh[nt], a0, 0, 0, 0);
                acc[mt][nt] = a0;
            }
        __syncthreads();
    }

    if constexpr (!LOGITS) {
        u16* Chb = Ch + (long)b * batchC;
        u16* Clb = Cl + (long)b * batchC;
#pragma unroll
        for (int mt = 0; mt < 4; ++mt)
#pragma unroll
            for (int nt = 0; nt < 4; ++nt)
#pragma unroll
                for (int r = 0; r < 4; ++r) {
                    int row = m0 + wm + mt * 16 + quad * 4 + r;
                    int col = n0 + wn + nt * 16 + l16;
                    float x = acc[mt][nt][r];
                    if (bias) x += bias[(long)row * N + col];
                    u16 h = f32_to_bf16(x);
                    u16 l = f32_to_bf16(x - bf16_to_f32(h));
                    Chb[(long)row * N + col] = h;
                    Clb[(long)row * N + col] = l;
                }
    } else {
        float cs[4] = {};
#pragma unroll
        for (int nt = 0; nt < 4; ++nt)
#pragma unroll
            for (int mt = 0; mt < 4; ++mt)
#pragma unroll
                for (int r = 0; r < 4; ++r) {
                    int row = m0 + wm + mt * 16 + quad * 4 + r;
                    cs[nt] = fmaf(w[row], fast_tanh(acc[mt][nt][r]), cs[nt]);
                }
        float* red = (float*)Ah;   // 8 x 128 floats (4 KB), safe post-loop
        const int r8 = (wave >> 1) * 4 + quad;
#pragma unroll
        for (int nt = 0; nt < 4; ++nt)
            red[r8 * 128 + wn + nt * 16 + l16] = cs[nt];
        __syncthreads();
        if (tid < 128) {
            float s = 0.f;
#pragma unroll
            for (int r = 0; r < 8; ++r) s += red[r * 128 + tid];
            atomicAdd(logits + (long)b * N + n0 + tid, s);
        }
    }
}

// ---------------- conversions ----------------
// elementwise split; grid*1024 must equal element count
__global__ __launch_bounds__(256) void split_kernel(
    const float* __restrict__ X, u16* __restrict__ Xh, u16* __restrict__ Xl)
{
    long i0 = ((long)blockIdx.x * 256 + threadIdx.x) * 4;
    float4 v = *(const float4*)(X + i0);
    float xs[4] = {v.x, v.y, v.z, v.w};
    u16 h[4], l[4];
#pragma unroll
    for (int i = 0; i < 4; ++i) {
        h[i] = f32_to_bf16(xs[i]);
        l[i] = f32_to_bf16(xs[i] - bf16_to_f32(h[i]));
    }
    *(ushort4*)(Xh + i0) = *(ushort4*)h;
    *(ushort4*)(Xl + i0) = *(ushort4*)l;
}

// transpose + split: src [b,R,C] -> dst [b,C,R]; grid (R/64, C/64, batch)
__global__ __launch_bounds__(256) void tsplit_kernel(
    const float* __restrict__ src, u16* __restrict__ dh, u16* __restrict__ dl,
    int R, int C)
{
    __shared__ float tile[64][65];
    const int b = blockIdx.z;
    const int r0 = blockIdx.x * 64, c0 = blockIdx.y * 64;
    const float* S = src + (long)b * R * C;
    const int t = threadIdx.x;
    const int lr = t >> 2, lc0 = (t & 3) * 16;
#pragma unroll
    for (int i = 0; i < 4; ++i)
        *(float4*)&tile[lr][lc0 + i * 4] =
            *(const float4*)(S + (long)(r0 + lr) * C + c0 + lc0 + i * 4);
    __syncthreads();
    u16 hbuf[16], lbuf[16];
#pragma unroll
    for (int i = 0; i < 16; ++i) {
        float x = tile[lc0 + i][lr];
        u16 hi = f32_to_bf16(x);
        hbuf[i] = hi;
        lbuf[i] = f32_to_bf16(x - bf16_to_f32(hi));
    }
    long o = (long)b * R * C + (long)(c0 + lr) * R + r0 + lc0;
    *(short8*)(dh + o)     = *(short8*)&hbuf[0];
    *(short8*)(dh + o + 8) = *(short8*)&hbuf[8];
    *(short8*)(dl + o)     = *(short8*)&lbuf[0];
    *(short8*)(dl + o + 8) = *(short8*)&lbuf[8];
}

// ---------------- fp32 GEMM (fallback tier only) ----------------
template <bool LOGITS>
__global__ __launch_bounds__(256) void gemm_core(
    const float* __restrict__ A, const float* __restrict__ Bm, float* __restrict__ C,
    const float* __restrict__ bias,
    int M, int N, int K,
    int sAm, int sAk, long batchA,
    int sBk, int sBn, long batchB,
    long batchC,
    const float* __restrict__ w, float* __restrict__ logits)
{
    __shared__ float As[BK][LDT];
    __shared__ float Bs[BK][LDT];
    const int tid = threadIdx.x;
    const int b   = blockIdx.z;
    const int m0  = blockIdx.y * BM;
    const int n0  = blockIdx.x * BN;
    const float* Ab = A  + (long)b * batchA;
    const float* Bb = Bm + (long)b * batchB;
    const int tm = tid >> 4, tn = tid & 15;
    float acc[8][8] = {};

    for (int k0 = 0; k0 < K; k0 += BK) {
        if (sAk == 1) {
#pragma unroll
            for (int i = 0; i < 2; ++i) {
                int idx = tid + i * 256;
                int m = idx >> 2, kg = (idx & 3) * 4;
                float4 v = *(const float4*)(Ab + (long)(m0 + m) * sAm + k0 + kg);
                As[kg+0][m] = v.x; As[kg+1][m] = v.y; As[kg+2][m] = v.z; As[kg+3][m] = v.w;
            }
        } else {
#pragma unroll
            for (int i = 0; i < 2; ++i) {
                int idx = tid + i * 256;
                int k = idx >> 5, mg = (idx & 31) * 4;
                float4 v = *(const float4*)(Ab + (long)(k0 + k) * sAk + m0 + mg);
                *(float4*)&As[k][mg] = v;
            }
        }
        if (sBn == 1) {
#pragma unroll
            for (int i = 0; i < 2; ++i) {
                int idx = tid + i * 256;
                int k = idx >> 5, ng = (idx & 31) * 4;
                float4 v = *(const float4*)(Bb + (long)(k0 + k) * sBk + n0 + ng);
                *(float4*)&Bs[k][ng] = v;
            }
        } else {
#pragma unroll
            for (int i = 0; i < 2; ++i) {
                int idx = tid + i * 256;
                int n = idx >> 2, kg = (idx & 3) * 4;
                float4 v = *(const float4*)(Bb + (long)(n0 + n) * sBn + k0 + kg);
                Bs[kg+0][n] = v.x; Bs[kg+1][n] = v.y; Bs[kg+2][n] = v.z; Bs[kg+3][n] = v.w;
            }
        }
        __syncthreads();
#pragma unroll
        for (int kk = 0; kk < BK; ++kk) {
            float a[8], bv[8];
            *(float4*)&a[0]  = *(const float4*)&As[kk][tm * 4];
            *(float4*)&a[4]  = *(const float4*)&As[kk][64 + tm * 4];
            *(float4*)&bv[0] = *(const float4*)&Bs[kk][tn * 4];
            *(float4*)&bv[4] = *(const float4*)&Bs[kk][64 + tn * 4];
#pragma unroll
            for (int i = 0; i < 8; ++i)
#pragma unroll
                for (int j = 0; j < 8; ++j)
                    acc[i][j] = fmaf(a[i], bv[j], acc[i][j]);
        }
        __syncthreads();
    }

    if constexpr (!LOGITS) {
        float* Cb = C + (long)b * batchC;
#pragma unroll
        for (int i = 0; i < 8; ++i) {
            int row = m0 + (i >> 2) * 64 + tm * 4 + (i & 3);
            float* crow = Cb + (long)row * N + n0;
            float4 o0 = {acc[i][0], acc[i][1], acc[i][2], acc[i][3]};
            float4 o1 = {acc[i][4], acc[i][5], acc[i][6], acc[i][7]};
            if (bias) {
                const float* brow = bias + (long)row * N + n0;
                float4 b0 = *(const float4*)(brow + tn * 4);
                float4 b1 = *(const float4*)(brow + 64 + tn * 4);
                o0.x += b0.x; o0.y += b0.y; o0.z += b0.z; o0.w += b0.w;
                o1.x += b1.x; o1.y += b1.y; o1.z += b1.z; o1.w += b1.w;
            }
            *(float4*)(crow + tn * 4) = o0;
            *(float4*)(crow + 64 + tn * 4) = o1;
        }
    } else {
        float wv[8];
#pragma unroll
        for (int i = 0; i < 8; ++i) wv[i] = w[m0 + (i >> 2) * 64 + tm * 4 + (i & 3)];
        float cs[8];
#pragma unroll
        for (int j = 0; j < 8; ++j) {
            float s = 0.f;
#pragma unroll
            for (int i = 0; i < 8; ++i) s = fmaf(wv[i], fast_tanh(acc[i][j]), s);
            cs[j] = s;
        }
        __syncthreads();
        *(float4*)&As[tm][tn * 4]      = *(float4*)&cs[0];
        *(float4*)&As[tm][64 + tn * 4] = *(float4*)&cs[4];
        __syncthreads();
        if (tid < 128) {
            float s = 0.f;
#pragma unroll
            for (int r = 0; r < 16; ++r) s += As[r][tid];
            atomicAdd(logits + (long)b * N + n0 + tid, s);
        }
    }
}

// ---------------- small kernels ----------------
__global__ __launch_bounds__(256) void softmax_kernel(
    const float* __restrict__ lv, const float* __restrict__ lq, float* __restrict__ out)
{
    const int b = blockIdx.x;
    const int which = blockIdx.y;
    const float* x = (which == 0 ? lv : lq) + (long)b * 2048;
    float* o = out + (long)which * (Bn * 2048) + (long)b * 2048;
    const int tid = threadIdx.x;
    __shared__ float sm[4], ss[4];

    float m = -3.4e38f;
    for (int i = tid; i < 2048; i += 256) m = fmaxf(m, x[i]);
    for (int off = 32; off > 0; off >>= 1) m = fmaxf(m, __shfl_down(m, off));
    if ((tid & 63) == 0) sm[tid >> 6] = m;
    __syncthreads();
    m = fmaxf(fmaxf(sm[0], sm[1]), fmaxf(sm[2], sm[3]));

    float s = 0.f;
    for (int i = tid; i < 2048; i += 256) s += expf(x[i] - m);
    for (int off = 32; off > 0; off >>= 1) s += __shfl_down(s, off);
    if ((tid & 63) == 0) ss[tid >> 6] = s;
    __syncthreads();
    s = ss[0] + ss[1] + ss[2] + ss[3];
    float inv = 1.0f / s;
    for (int i = tid; i < 2048; i += 256) o[i] = expf(x[i] - m) * inv;
}

__global__ __launch_bounds__(256) void vout_kernel(
    const float* __restrict__ V, const float* __restrict__ av, float* __restrict__ vout)
{
    const int wave = threadIdx.x >> 6, lane = threadIdx.x & 63;
    const long idx = (long)blockIdx.x * 4 + wave;
    const int b = (int)(idx >> 10);
    const int h = (int)(idx & 1023);
    const float* vp = V + ((long)b * Hd + h) * NVn;
    const float* ap = av + (long)b * NVn;
    float s = 0.f;
    for (int i = lane; i < NVn; i += 64) s = fmaf(ap[i], vp[i], s);
    for (int off = 32; off > 0; off >>= 1) s += __shfl_down(s, off);
    if (lane == 0) vout[idx] = s;
}

__global__ __launch_bounds__(256) void qout_kernel(
    const float* __restrict__ Q, const float* __restrict__ aq, float* __restrict__ qout)
{
    const int h  = blockIdx.x * 256 + threadIdx.x;
    const int b  = blockIdx.z;
    const int q0 = blockIdx.y * 256;
    const float* qp = Q + (long)b * NQn * Hd;
    const float* ap = aq + (long)b * NQn + q0;
    float s = 0.f;
    for (int q = 0; q < 256; ++q) s = fmaf(ap[q], qp[(long)(q0 + q) * Hd + h], s);
    atomicAdd(qout + (long)b * Hd + h, s);
}

extern "C" void kernel_launch(void* const* d_in, const int* in_sizes, int n_in,
                              void* d_out, int out_size, void* d_ws, size_t ws_size,
                              hipStream_t stream) {
    const float* V    = (const float*)d_in[0];
    const float* Q    = (const float*)d_in[1];
    const float* W_b  = (const float*)d_in[2];
    const float* W_v  = (const float*)d_in[3];
    const float* W_q  = (const float*)d_in[4];
    const float* w_hv = (const float*)d_in[5];
    const float* w_hq = (const float*)d_in[6];
    float* out = (float*)d_out;
    dim3 blk(256);

    const long BIG  = (long)Bn * Hd * NVn;   // 33.55M (one big matrix, one half)
    const long GEL  = (long)Bn * Hd * Hd;    // 16.78M
    const long TEL  = (long)Bn * COn * Hd;   // 8.39M
    const long WQE  = (long)COn * Hd;        // 0.52M
    const long WBE  = (long)Hd * Hd;         // 1.05M

    // u16 layout
    u16* ws16 = (u16*)d_ws;
    u16* R1h  = ws16;            u16* R1l  = R1h + BIG;      // 134 MB shared region
    u16* Gh   = R1l + BIG;       u16* Gl   = Gh + GEL;       // 67 MB
    u16* Th   = Gl + GEL;        u16* Tl   = Th + TEL;       // 33.5 MB
    u16* Uh   = Gh;              u16* Ul   = Gh + TEL;       // U aliases dead G
    u16* Wqh  = Tl + TEL;        u16* Wql  = Wqh + WQE;
    u16* Wvh  = Wql + WQE;       u16* Wvl  = Wvh + WQE;
    u16* Wbh  = Wvl + WQE;       u16* Wbl  = Wbh + WBE;
    u16* WbTh = Wbl + WBE;       u16* WbTl = WbTh + WBE;
    float* lv = (float*)(WbTl + WBE);
    float* lq = lv + Bn * NVn;
    const size_t need = (size_t)((u16*)(lq + Bn * NQn) - ws16) * 2;

    float* vout_p = out + 2 * Bn * NVn;
    float* qout_p = vout_p + Bn * Hd;

    if (ws_size >= need) {
        hipMemsetAsync(lv, 0, (size_t)(Bn * NVn + Bn * NQn) * sizeof(float), stream);
        hipMemsetAsync(qout_p, 0, (size_t)Bn * Hd * sizeof(float), stream);

        // weight splits
        split_kernel<<<dim3((unsigned)(WQE / 1024)), blk, 0, stream>>>(W_q, Wqh, Wql);
        split_kernel<<<dim3((unsigned)(WQE / 1024)), blk, 0, stream>>>(W_v, Wvh, Wvl);
        split_kernel<<<dim3((unsigned)(WBE / 1024)), blk, 0, stream>>>(W_b, Wbh, Wbl);
        tsplit_kernel<<<dim3(Hd / 64, Hd / 64, 1), blk, 0, stream>>>(W_b, WbTh, WbTl, Hd, Hd);

        // ---- chain Q ----
        tsplit_kernel<<<dim3(NQn / 64, Hd / 64, Bn), blk, 0, stream>>>(Q, R1h, R1l, NQn, Hd);
        // G_Q = QT QT^T  [Hd,Hd]  (256^2 phase-split kernel)
        mm8p<false><<<dim3((Hd / 256) * (Hd / 256) * Bn), dim3(512), 0, stream>>>(
            R1h, R1l, (long)Hd * NQn, NQn,  R1h, R1l, (long)Hd * NQn, NQn,
            Hd, NQn, Hd / 256, Hd / 256,
            nullptr, Gh, Gl, (long)Hd * Hd, nullptr, nullptr);
        // T = W_q @ G (G symmetric: B = G k-contig)
        mm3<false><<<dim3(Hd / 128, COn / 128, Bn), blk, 0, stream>>>(
            Wqh, Wql, 0L, Hd,  Gh, Gl, (long)Hd * Hd, Hd,
            Hd, Hd, nullptr, Th, Tl, (long)COn * Hd, nullptr, nullptr);
        // U = T @ W_b + W_v  (B = W_b^T pre-transposed)
        mm3<false><<<dim3(Hd / 128, COn / 128, Bn), blk, 0, stream>>>(
            Th, Tl, (long)COn * Hd, Hd,  WbTh, WbTl, 0L, Hd,
            Hd, Hd, W_v, Uh, Ul, (long)COn * Hd, nullptr, nullptr);
        // VT for logits B operand (QT dead)
        tsplit_kernel<<<dim3(Hd / 64, NVn / 64, Bn), blk, 0, stream>>>(V, R1h, R1l, Hd, NVn);
        // logits_v += w_hv . tanh(U @ V)
        mm8p<true><<<dim3((NVn / 256) * (COn / 256) * Bn), dim3(512), 0, stream>>>(
            Uh, Ul, (long)COn * Hd, Hd,  R1h, R1l, (long)NVn * Hd, Hd,
            NVn, Hd, NVn / 256, COn / 256,
            nullptr, nullptr, nullptr, 0L, w_hv, lv);

        // ---- chain V ----
        split_kernel<<<dim3((unsigned)(BIG / 1024)), blk, 0, stream>>>(V, R1h, R1l);
        // G_V = V V^T
        mm8p<false><<<dim3((Hd / 256) * (Hd / 256) * Bn), dim3(512), 0, stream>>>(
            R1h, R1l, (long)Hd * NVn, NVn,  R1h, R1l, (long)Hd * NVn, NVn,
            Hd, NVn, Hd / 256, Hd / 256,
            nullptr, Gh, Gl, (long)Hd * Hd, nullptr, nullptr);
        // T = W_v @ G
        mm3<false><<<dim3(Hd / 128, COn / 128, Bn), blk, 0, stream>>>(
            Wvh, Wvl, 0L, Hd,  Gh, Gl, (long)Hd * Hd, Hd,
            Hd, Hd, nullptr, Th, Tl, (long)COn * Hd, nullptr, nullptr);
        // U = T @ W_b^T + W_q  (B = W_b row-major already [n,k])
        mm3<false><<<dim3(Hd / 128, COn / 128, Bn), blk, 0, stream>>>(
            Th, Tl, (long)COn * Hd, Hd,  Wbh, Wbl, 0L, Hd,
            Hd, Hd, W_q, Uh, Ul, (long)COn * Hd, nullptr, nullptr);
        // Q split (elementwise) for logits B operand (Vsplit dead)
        split_kernel<<<dim3((unsigned)(BIG / 1024)), blk, 0, stream>>>(Q, R1h, R1l);
        // logits_q += w_hq . tanh(U @ Q^T)
        mm8p<true><<<dim3((NQn / 256) * (COn / 256) * Bn), dim3(512), 0, stream>>>(
            Uh, Ul, (long)COn * Hd, Hd,  R1h, R1l, (long)NQn * Hd, Hd,
            NQn, Hd, NQn / 256, COn / 256,
            nullptr, nullptr, nullptr, 0L, w_hq, lq);

        softmax_kernel<<<dim3(Bn, 2), blk, 0, stream>>>(lv, lq, out);
        vout_kernel<<<dim3(Bn * Hd / 4), blk, 0, stream>>>(V, out, vout_p);
        qout_kernel<<<dim3(Hd / 256, NQn / 256, Bn), blk, 0, stream>>>(Q, out + Bn * NVn, qout_p);
        return;
    }

    // ---------------- fp32 fallback tier ----------------
    float* ws = (float*)d_ws;
    float* g  = ws;
    float* t  = g + GEL;
    float* u  = t + TEL;
    float* flv = u + TEL;
    float* flq = flv + Bn * NVn;

    hipMemsetAsync(flv, 0, (size_t)(Bn * NVn + Bn * NQn) * sizeof(float), stream);
    hipMemsetAsync(qout_p, 0, (size_t)Bn * Hd * sizeof(float), stream);

    gemm_core<false><<<dim3(Hd/BN, Hd/BM, Bn), blk, 0, stream>>>(Q, Q, g, nullptr,
        Hd, Hd, NQn, 1, Hd, (long)NQn*Hd, Hd, 1, (long)NQn*Hd, (long)Hd*Hd, nullptr, nullptr);
    gemm_core<false><<<dim3(Hd/BN, COn/BM, Bn), blk, 0, stream>>>(W_q, g, t, nullptr,
        COn, Hd, Hd, Hd, 1, 0L, Hd, 1, (long)Hd*Hd, (long)COn*Hd, nullptr, nullptr);
    gemm_core<false><<<dim3(Hd/BN, COn/BM, Bn), blk, 0, stream>>>(t, W_b, u, W_v,
        COn, Hd, Hd, Hd, 1, (long)COn*Hd, Hd, 1, 0L, (long)COn*Hd, nullptr, nullptr);
    gemm_core<true><<<dim3(NVn/BN, COn/BM, Bn), blk, 0, stream>>>(
        u, V, nullptr, nullptr, COn, NVn, Hd,
        Hd, 1, (long)COn*Hd, NVn, 1, (long)Hd*NVn, 0L, w_hv, flv);
    gemm_core<false><<<dim3(Hd/BN, Hd/BM, Bn), blk, 0, stream>>>(V, V, g, nullptr,
        Hd, Hd, NVn, NVn, 1, (long)Hd*NVn, 1, NVn, (long)Hd*NVn, (long)Hd*Hd, nullptr, nullptr);
    gemm_core<false><<<dim3(Hd/BN, COn/BM, Bn), blk, 0, stream>>>(W_v, g, t, nullptr,
        COn, Hd, Hd, Hd, 1, 0L, Hd, 1, (long)Hd*Hd, (long)COn*Hd, nullptr, nullptr);
    gemm_core<false><<<dim3(Hd/BN, COn/BM, Bn), blk, 0, stream>>>(t, W_b, u, W_q,
        COn, Hd, Hd, Hd, 1, (long)COn*Hd, 1, Hd, 0L, (long)COn*Hd, nullptr, nullptr);
    gemm_core<true><<<dim3(NQn/BN, COn/BM, Bn), blk, 0, stream>>>(
        u, Q, nullptr, nullptr, COn, NQn, Hd,
        Hd, 1, (long)COn*Hd, 1, Hd, (long)NQn*Hd, 0L, w_hq, flq);

    softmax_kernel<<<dim3(Bn, 2), blk, 0, stream>>>(flv, flq, out);
    vout_kernel<<<dim3(Bn * Hd / 4), blk, 0, stream>>>(V, out, vout_p);
    qout_kernel<<<dim3(Hd / 256, NQn / 256, Bn), blk, 0, stream>>>(Q, out + Bn * NVn, qout_p);
}

// Round 5
// 1203.600 us; speedup vs baseline: 1.4118x; 1.0442x over previous
//
#include <hip/hip_runtime.h>
#include <math.h>

#define Bn  16
#define Hd  1024
#define COn 512
#define NVn 2048
#define NQn 2048

#define BM 128
#define BN 128
#define BK 16
#define LDT 132

typedef unsigned short u16;
typedef __attribute__((ext_vector_type(8))) short short8;
typedef __attribute__((ext_vector_type(4))) float floatx4;

__device__ __forceinline__ float fast_tanh(float x) {
    float ax = fabsf(x);
    float e  = __expf(2.0f * ax);
    float t  = 1.0f - 2.0f / (e + 1.0f);
    return copysignf(t, x);
}

__device__ __forceinline__ u16 f32_to_bf16(float x) {
    unsigned u = __float_as_uint(x);
    unsigned r = (u + 0x7fffu + ((u >> 16) & 1u)) >> 16;   // RNE, finite inputs
    return (u16)r;
}
__device__ __forceinline__ float bf16_to_f32(u16 h) {
    return __uint_as_float(((unsigned)h) << 16);
}

// async global->LDS, 16B per lane. LDS dest is wave-uniform base + lane*16.
__device__ __forceinline__ void gload16(const u16* g, u16* l) {
    __builtin_amdgcn_global_load_lds(
        (__attribute__((address_space(1))) void*)(g),
        (__attribute__((address_space(3))) void*)(l), 16, 0, 0);
}

// ================= 256x256 8-wave bf16x3 GEMM (unchanged from r4) =================
// C = A*B (+bias): A [M,K] k-contig hi/lo, B TRANSPOSED [N,K] k-contig hi/lo.
// grid = gx*gy*Bn (1D, XCD-swizzled), block = 512.  K mult of 32 (>=64).
// LDS row-major 64B rows; in-row rotated k-slot (unit u holds kslot
// u ^ ((row>>1)&3)): conflict-free reads + coalesced staging.
// ONE vmcnt(0)+barrier per K-tile; waves drift; setprio around MFMA.
template <bool LOGITS>
__global__ __launch_bounds__(512, 2) void mm8p(
    const u16* __restrict__ Ahp, const u16* __restrict__ Alp, long batchA, int ldA,
    const u16* __restrict__ Bhp, const u16* __restrict__ Blp, long batchB, int ldB,
    int N, int K, int gx, int gy,
    const float* __restrict__ bias,
    u16* __restrict__ Ch, u16* __restrict__ Cl, long batchC,
    const float* __restrict__ w, float* __restrict__ logits)
{
    __shared__ u16 lds[2][4][256 * 32];   // 128 KiB: [buf][Ah,Al,Bh,Bl][row][k]

    const int tid = threadIdx.x;
    // bijective XCD-chunked swizzle
    const int nwg = (int)gridDim.x;
    int bid = (int)blockIdx.x;
    {
        int q = nwg >> 3, r = nwg & 7, xcd = bid & 7, idx = bid >> 3;
        bid = (xcd < r ? xcd * (q + 1) : r * (q + 1) + (xcd - r) * q) + idx;
    }
    const int bpz = gx * gy;
    const int b    = bid / bpz;
    const int brem = bid - b * bpz;
    const int m0 = (brem / gx) * 256;
    const int n0 = (brem % gx) * 256;

    const u16* Ahb = Ahp + (long)b * batchA;
    const u16* Alb = Alp + (long)b * batchA;
    const u16* Bhb = Bhp + (long)b * batchB;
    const u16* Blb = Blp + (long)b * batchB;

    const int wave = tid >> 6, lane = tid & 63;
    const int quad = lane >> 4, l16 = lane & 15;
    const int xsl = (quad ^ ((l16 >> 1) & 3)) * 8;   // in-row rotated k-slot (u16 units)
    const int wm = (wave >> 2) * 128;      // 2 wave-rows
    const int wn = (wave & 3) * 64;        // 4 wave-cols

    // staging role: wave w stages matrix (w>>1), rows [(w&1)*128, +128)
    const int smat  = wave >> 1;           // 0=Ah 1=Al 2=Bh 3=Bl
    const int srow0 = (wave & 1) * 128;
    const int srl   = lane >> 2;           // row within 16-row chunk
    const int kx    = ((lane & 3) ^ ((lane >> 3) & 3)) * 8;  // rotated source k-slot
    const u16* srcp = smat == 0 ? Ahb : smat == 1 ? Alb : smat == 2 ? Bhb : Blb;
    const long sld  = (smat < 2) ? ldA : ldB;
    const int rowbase = (smat < 2) ? m0 : n0;
    const u16* sp = srcp + (long)(rowbase + srow0 + srl) * sld + kx;

    floatx4 acc[8][4] = {};

    // prologue: stage K-tile 0 into buf 0
#pragma unroll
    for (int j = 0; j < 8; ++j)
        gload16(sp + (long)j * 16 * sld, &lds[0][smat][(srow0 + j * 16) * 32]);
    asm volatile("s_waitcnt vmcnt(0)" ::: "memory");
    __builtin_amdgcn_s_barrier();

    const int NT = K >> 5;
    for (int t = 0; t < NT; ++t) {
        const int  cur = t & 1;
        const bool pf  = (t + 1 < NT);
        const long k0n = (long)(t + 1) * 32;
        const u16* Ah_ = &lds[cur][0][0];
        const u16* Al_ = &lds[cur][1][0];
        const u16* Bh_ = &lds[cur][2][0];
        const u16* Bl_ = &lds[cur][3][0];

        short8 bh[4], bl[4];
#pragma unroll
        for (int nt = 0; nt < 4; ++nt) {
            const int bs = (wn + nt * 16 + l16) * 32 + xsl;
            bh[nt] = *(const short8*)&Bh_[bs];
            bl[nt] = *(const short8*)&Bl_[bs];
        }
        if (pf) {   // issue next-tile stages early; whole tile of MFMA covers them
            u16* dst = &lds[cur ^ 1][smat][srow0 * 32];
#pragma unroll
            for (int j = 0; j < 8; ++j)
                gload16(sp + (long)j * 16 * sld + k0n, dst + j * 16 * 32);
        }
#pragma unroll
        for (int p = 0; p < 4; ++p) {
            const int as0 = (wm + p * 32 + l16) * 32 + xsl;
            const int as1 = as0 + 16 * 32;
            const short8 a0h = *(const short8*)&Ah_[as0];
            const short8 a0l = *(const short8*)&Al_[as0];
            const short8 a1h = *(const short8*)&Ah_[as1];
            const short8 a1l = *(const short8*)&Al_[as1];
            __builtin_amdgcn_s_setprio(1);
#pragma unroll
            for (int nt = 0; nt < 4; ++nt) {
                floatx4 c0 = acc[2 * p][nt];
                c0 = __builtin_amdgcn_mfma_f32_16x16x32_bf16(a0h, bh[nt], c0, 0, 0, 0);
                c0 = __builtin_amdgcn_mfma_f32_16x16x32_bf16(a0h, bl[nt], c0, 0, 0, 0);
                c0 = __builtin_amdgcn_mfma_f32_16x16x32_bf16(a0l, bh[nt], c0, 0, 0, 0);
                acc[2 * p][nt] = c0;
                floatx4 c1 = acc[2 * p + 1][nt];
                c1 = __builtin_amdgcn_mfma_f32_16x16x32_bf16(a1h, bh[nt], c1, 0, 0, 0);
                c1 = __builtin_amdgcn_mfma_f32_16x16x32_bf16(a1h, bl[nt], c1, 0, 0, 0);
                c1 = __builtin_amdgcn_mfma_f32_16x16x32_bf16(a1l, bh[nt], c1, 0, 0, 0);
                acc[2 * p + 1][nt] = c1;
            }
            __builtin_amdgcn_s_setprio(0);
        }
        if (pf) asm volatile("s_waitcnt vmcnt(0)" ::: "memory");
        __builtin_amdgcn_s_barrier();
    }

    if constexpr (!LOGITS) {
        u16* Chb = Ch + (long)b * batchC;
        u16* Clb = Cl + (long)b * batchC;
#pragma unroll
        for (int mt = 0; mt < 8; ++mt)
#pragma unroll
            for (int nt = 0; nt < 4; ++nt)
#pragma unroll
                for (int r = 0; r < 4; ++r) {
                    const int row = m0 + wm + mt * 16 + quad * 4 + r;
                    const int col = n0 + wn + nt * 16 + l16;
                    float x = acc[mt][nt][r];
                    if (bias) x += bias[(long)row * N + col];
                    const u16 h = f32_to_bf16(x);
                    Chb[(long)row * N + col] = h;
                    Clb[(long)row * N + col] = f32_to_bf16(x - bf16_to_f32(h));
                }
    } else {
        float cs[4] = {};
#pragma unroll
        for (int nt = 0; nt < 4; ++nt)
#pragma unroll
            for (int mt = 0; mt < 8; ++mt)
#pragma unroll
                for (int r = 0; r < 4; ++r) {
                    const int row = m0 + wm + mt * 16 + quad * 4 + r;
                    cs[nt] = fmaf(w[row], fast_tanh(acc[mt][nt][r]), cs[nt]);
                }
        float* red = (float*)&lds[0][0][0];   // 8 x 256 f32 (8 KB), safe post-loop
        const int r8 = (wave >> 2) * 4 + quad;
#pragma unroll
        for (int nt = 0; nt < 4; ++nt)
            red[r8 * 256 + wn + nt * 16 + l16] = cs[nt];
        __syncthreads();
        if (tid < 256) {
            float s = 0.f;
#pragma unroll
            for (int r = 0; r < 8; ++r) s += red[r * 256 + tid];
            atomicAdd(logits + (long)b * N + n0 + tid, s);
        }
    }
}

// ================= 128x128 4-wave bf16x3 GEMM (mm8p structure at 128^2) =====
// For T/U stages. Wave w stages matrix w (128 rows = 8 gloads). 64 KiB LDS
// -> 2 blocks/CU. Same rotated k-slot layout, ONE vmcnt+barrier per K-tile.
__global__ __launch_bounds__(256, 2) void mm4(
    const u16* __restrict__ Ahp, const u16* __restrict__ Alp, long batchA, int ldA,
    const u16* __restrict__ Bhp, const u16* __restrict__ Blp, long batchB, int ldB,
    int N, int K,
    const float* __restrict__ bias,
    u16* __restrict__ Ch, u16* __restrict__ Cl, long batchC)
{
    __shared__ u16 lds[2][4][128 * 32];   // 64 KiB

    const int tid = threadIdx.x;
    const int b   = blockIdx.z;
    const int m0  = blockIdx.y * 128;
    const int n0  = blockIdx.x * 128;
    const u16* Ahb = Ahp + (long)b * batchA;
    const u16* Alb = Alp + (long)b * batchA;
    const u16* Bhb = Bhp + (long)b * batchB;
    const u16* Blb = Blp + (long)b * batchB;

    const int wave = tid >> 6, lane = tid & 63;
    const int quad = lane >> 4, l16 = lane & 15;
    const int xsl = (quad ^ ((l16 >> 1) & 3)) * 8;
    const int wm = (wave >> 1) * 64, wn = (wave & 1) * 64;

    // staging: wave w owns matrix w entirely (128 rows, 8 gloads)
    const int smat = wave;
    const int kx   = ((lane & 3) ^ ((lane >> 3) & 3)) * 8;
    const u16* srcp = smat == 0 ? Ahb : smat == 1 ? Alb : smat == 2 ? Bhb : Blb;
    const long sld  = (smat < 2) ? ldA : ldB;
    const int rowbase = (smat < 2) ? m0 : n0;
    const u16* sp = srcp + (long)(rowbase + (lane >> 2)) * sld + kx;

    floatx4 acc[4][4] = {};

#pragma unroll
    for (int j = 0; j < 8; ++j)
        gload16(sp + (long)j * 16 * sld, &lds[0][smat][j * 16 * 32]);
    asm volatile("s_waitcnt vmcnt(0)" ::: "memory");
    __builtin_amdgcn_s_barrier();

    const int NT = K >> 5;
    for (int t = 0; t < NT; ++t) {
        const int  cur = t & 1;
        const bool pf  = (t + 1 < NT);
        const long k0n = (long)(t + 1) * 32;

        short8 ah[4], al[4], bh[4], bl[4];
#pragma unroll
        for (int t4 = 0; t4 < 4; ++t4) {
            const int as = (wm + t4 * 16 + l16) * 32 + xsl;
            ah[t4] = *(const short8*)&lds[cur][0][as];
            al[t4] = *(const short8*)&lds[cur][1][as];
            const int bs = (wn + t4 * 16 + l16) * 32 + xsl;
            bh[t4] = *(const short8*)&lds[cur][2][bs];
            bl[t4] = *(const short8*)&lds[cur][3][bs];
        }
        if (pf) {
            u16* dst = &lds[cur ^ 1][smat][0];
#pragma unroll
            for (int j = 0; j < 8; ++j)
                gload16(sp + (long)j * 16 * sld + k0n, dst + j * 16 * 32);
        }
        __builtin_amdgcn_s_setprio(1);
#pragma unroll
        for (int mt = 0; mt < 4; ++mt)
#pragma unroll
            for (int nt = 0; nt < 4; ++nt) {
                floatx4 a0 = acc[mt][nt];
                a0 = __builtin_amdgcn_mfma_f32_16x16x32_bf16(ah[mt], bh[nt], a0, 0, 0, 0);
                a0 = __builtin_amdgcn_mfma_f32_16x16x32_bf16(ah[mt], bl[nt], a0, 0, 0, 0);
                a0 = __builtin_amdgcn_mfma_f32_16x16x32_bf16(al[mt], bh[nt], a0, 0, 0, 0);
                acc[mt][nt] = a0;
            }
        __builtin_amdgcn_s_setprio(0);
        if (pf) asm volatile("s_waitcnt vmcnt(0)" ::: "memory");
        __builtin_amdgcn_s_barrier();
    }

    u16* Chb = Ch + (long)b * batchC;
    u16* Clb = Cl + (long)b * batchC;
#pragma unroll
    for (int mt = 0; mt < 4; ++mt)
#pragma unroll
        for (int nt = 0; nt < 4; ++nt)
#pragma unroll
            for (int r = 0; r < 4; ++r) {
                int row = m0 + wm + mt * 16 + quad * 4 + r;
                int col = n0 + wn + nt * 16 + l16;
                float x = acc[mt][nt][r];
                if (bias) x += bias[(long)row * N + col];
                u16 h = f32_to_bf16(x);
                u16 l = f32_to_bf16(x - bf16_to_f32(h));
                Chb[(long)row * N + col] = h;
                Clb[(long)row * N + col] = l;
            }
}

// ---------------- conversions ----------------
// elementwise split; grid*1024 must equal element count
__global__ __launch_bounds__(256) void split_kernel(
    const float* __restrict__ X, u16* __restrict__ Xh, u16* __restrict__ Xl)
{
    long i0 = ((long)blockIdx.x * 256 + threadIdx.x) * 4;
    float4 v = *(const float4*)(X + i0);
    float xs[4] = {v.x, v.y, v.z, v.w};
    u16 h[4], l[4];
#pragma unroll
    for (int i = 0; i < 4; ++i) {
        h[i] = f32_to_bf16(xs[i]);
        l[i] = f32_to_bf16(xs[i] - bf16_to_f32(h[i]));
    }
    *(ushort4*)(Xh + i0) = *(ushort4*)h;
    *(ushort4*)(Xl + i0) = *(ushort4*)l;
}

// transpose + split: src [b,R,C] -> dst [b,C,R]; grid (R/64, C/64, batch)
__global__ __launch_bounds__(256) void tsplit_kernel(
    const float* __restrict__ src, u16* __restrict__ dh, u16* __restrict__ dl,
    int R, int C)
{
    __shared__ float tile[64][65];
    const int b = blockIdx.z;
    const int r0 = blockIdx.x * 64, c0 = blockIdx.y * 64;
    const float* S = src + (long)b * R * C;
    const int t = threadIdx.x;
    const int lr = t >> 2, lc0 = (t & 3) * 16;
#pragma unroll
    for (int i = 0; i < 4; ++i)
        *(float4*)&tile[lr][lc0 + i * 4] =
            *(const float4*)(S + (long)(r0 + lr) * C + c0 + lc0 + i * 4);
    __syncthreads();
    u16 hbuf[16], lbuf[16];
#pragma unroll
    for (int i = 0; i < 16; ++i) {
        float x = tile[lc0 + i][lr];
        u16 hi = f32_to_bf16(x);
        hbuf[i] = hi;
        lbuf[i] = f32_to_bf16(x - bf16_to_f32(hi));
    }
    long o = (long)b * R * C + (long)(c0 + lr) * R + r0 + lc0;
    *(short8*)(dh + o)     = *(short8*)&hbuf[0];
    *(short8*)(dh + o + 8) = *(short8*)&hbuf[8];
    *(short8*)(dl + o)     = *(short8*)&lbuf[0];
    *(short8*)(dl + o + 8) = *(short8*)&lbuf[8];
}

// fused transpose-split + straight-split: one read of src produces
// dT (transposed [b,C,R] hi/lo) AND d (straight [b,R,C] hi/lo).
__global__ __launch_bounds__(256) void tsplit2_kernel(
    const float* __restrict__ src,
    u16* __restrict__ dTh, u16* __restrict__ dTl,
    u16* __restrict__ dh,  u16* __restrict__ dl,
    int R, int C)
{
    __shared__ float tile[64][65];
    const int b = blockIdx.z;
    const int r0 = blockIdx.x * 64, c0 = blockIdx.y * 64;
    const float* S = src + (long)b * R * C;
    const int t = threadIdx.x;
    const int lr = t >> 2, lc0 = (t & 3) * 16;
    float4 v[4];
#pragma unroll
    for (int i = 0; i < 4; ++i) {
        v[i] = *(const float4*)(S + (long)(r0 + lr) * C + c0 + lc0 + i * 4);
        *(float4*)&tile[lr][lc0 + i * 4] = v[i];
    }
    // straight split from registers
    {
        u16 sh[16], sl[16];
#pragma unroll
        for (int i = 0; i < 4; ++i) {
            float xs[4] = {v[i].x, v[i].y, v[i].z, v[i].w};
#pragma unroll
            for (int j = 0; j < 4; ++j) {
                u16 hi = f32_to_bf16(xs[j]);
                sh[i * 4 + j] = hi;
                sl[i * 4 + j] = f32_to_bf16(xs[j] - bf16_to_f32(hi));
            }
        }
        long os = (long)b * R * C + (long)(r0 + lr) * C + c0 + lc0;
        *(short8*)(dh + os)     = *(short8*)&sh[0];
        *(short8*)(dh + os + 8) = *(short8*)&sh[8];
        *(short8*)(dl + os)     = *(short8*)&sl[0];
        *(short8*)(dl + os + 8) = *(short8*)&sl[8];
    }
    __syncthreads();
    u16 hbuf[16], lbuf[16];
#pragma unroll
    for (int i = 0; i < 16; ++i) {
        float x = tile[lc0 + i][lr];
        u16 hi = f32_to_bf16(x);
        hbuf[i] = hi;
        lbuf[i] = f32_to_bf16(x - bf16_to_f32(hi));
    }
    long o = (long)b * R * C + (long)(c0 + lr) * R + r0 + lc0;
    *(short8*)(dTh + o)     = *(short8*)&hbuf[0];
    *(short8*)(dTh + o + 8) = *(short8*)&hbuf[8];
    *(short8*)(dTl + o)     = *(short8*)&lbuf[0];
    *(short8*)(dTl + o + 8) = *(short8*)&lbuf[8];
}

// ---------------- fp32 GEMM (fallback tier only) ----------------
template <bool LOGITS>
__global__ __launch_bounds__(256) void gemm_core(
    const float* __restrict__ A, const float* __restrict__ Bm, float* __restrict__ C,
    const float* __restrict__ bias,
    int M, int N, int K,
    int sAm, int sAk, long batchA,
    int sBk, int sBn, long batchB,
    long batchC,
    const float* __restrict__ w, float* __restrict__ logits)
{
    __shared__ float As[BK][LDT];
    __shared__ float Bs[BK][LDT];
    const int tid = threadIdx.x;
    const int b   = blockIdx.z;
    const int m0  = blockIdx.y * BM;
    const int n0  = blockIdx.x * BN;
    const float* Ab = A  + (long)b * batchA;
    const float* Bb = Bm + (long)b * batchB;
    const int tm = tid >> 4, tn = tid & 15;
    float acc[8][8] = {};

    for (int k0 = 0; k0 < K; k0 += BK) {
        if (sAk == 1) {
#pragma unroll
            for (int i = 0; i < 2; ++i) {
                int idx = tid + i * 256;
                int m = idx >> 2, kg = (idx & 3) * 4;
                float4 v = *(const float4*)(Ab + (long)(m0 + m) * sAm + k0 + kg);
                As[kg+0][m] = v.x; As[kg+1][m] = v.y; As[kg+2][m] = v.z; As[kg+3][m] = v.w;
            }
        } else {
#pragma unroll
            for (int i = 0; i < 2; ++i) {
                int idx = tid + i * 256;
                int k = idx >> 5, mg = (idx & 31) * 4;
                float4 v = *(const float4*)(Ab + (long)(k0 + k) * sAk + m0 + mg);
                *(float4*)&As[k][mg] = v;
            }
        }
        if (sBn == 1) {
#pragma unroll
            for (int i = 0; i < 2; ++i) {
                int idx = tid + i * 256;
                int k = idx >> 5, ng = (idx & 31) * 4;
                float4 v = *(const float4*)(Bb + (long)(k0 + k) * sBk + n0 + ng);
                *(float4*)&Bs[k][ng] = v;
            }
        } else {
#pragma unroll
            for (int i = 0; i < 2; ++i) {
                int idx = tid + i * 256;
                int n = idx >> 2, kg = (idx & 3) * 4;
                float4 v = *(const float4*)(Bb + (long)(n0 + n) * sBn + k0 + kg);
                Bs[kg+0][n] = v.x; Bs[kg+1][n] = v.y; Bs[kg+2][n] = v.z; Bs[kg+3][n] = v.w;
            }
        }
        __syncthreads();
#pragma unroll
        for (int kk = 0; kk < BK; ++kk) {
            float a[8], bv[8];
            *(float4*)&a[0]  = *(const float4*)&As[kk][tm * 4];
            *(float4*)&a[4]  = *(const float4*)&As[kk][64 + tm * 4];
            *(float4*)&bv[0] = *(const float4*)&Bs[kk][tn * 4];
            *(float4*)&bv[4] = *(const float4*)&Bs[kk][64 + tn * 4];
#pragma unroll
            for (int i = 0; i < 8; ++i)
#pragma unroll
                for (int j = 0; j < 8; ++j)
                    acc[i][j] = fmaf(a[i], bv[j], acc[i][j]);
        }
        __syncthreads();
    }

    if constexpr (!LOGITS) {
        float* Cb = C + (long)b * batchC;
#pragma unroll
        for (int i = 0; i < 8; ++i) {
            int row = m0 + (i >> 2) * 64 + tm * 4 + (i & 3);
            float* crow = Cb + (long)row * N + n0;
            float4 o0 = {acc[i][0], acc[i][1], acc[i][2], acc[i][3]};
            float4 o1 = {acc[i][4], acc[i][5], acc[i][6], acc[i][7]};
            if (bias) {
                const float* brow = bias + (long)row * N + n0;
                float4 b0 = *(const float4*)(brow + tn * 4);
                float4 b1 = *(const float4*)(brow + 64 + tn * 4);
                o0.x += b0.x; o0.y += b0.y; o0.z += b0.z; o0.w += b0.w;
                o1.x += b1.x; o1.y += b1.y; o1.z += b1.z; o1.w += b1.w;
            }
            *(float4*)(crow + tn * 4) = o0;
            *(float4*)(crow + 64 + tn * 4) = o1;
        }
    } else {
        float wv[8];
#pragma unroll
        for (int i = 0; i < 8; ++i) wv[i] = w[m0 + (i >> 2) * 64 + tm * 4 + (i & 3)];
        float cs[8];
#pragma unroll
        for (int j = 0; j < 8; ++j) {
            float s = 0.f;
#pragma unroll
            for (int i = 0; i < 8; ++i) s = fmaf(wv[i], fast_tanh(acc[i][j]), s);
            cs[j] = s;
        }
        __syncthreads();
        *(float4*)&As[tm][tn * 4]      = *(float4*)&cs[0];
        *(float4*)&As[tm][64 + tn * 4] = *(float4*)&cs[4];
        __syncthreads();
        if (tid < 128) {
            float s = 0.f;
#pragma unroll
            for (int r = 0; r < 16; ++r) s += As[r][tid];
            atomicAdd(logits + (long)b * N + n0 + tid, s);
        }
    }
}

// ---------------- small kernels ----------------
__global__ __launch_bounds__(256) void softmax_kernel(
    const float* __restrict__ lv, const float* __restrict__ lq, float* __restrict__ out)
{
    const int b = blockIdx.x;
    const int which = blockIdx.y;
    const float* x = (which == 0 ? lv : lq) + (long)b * 2048;
    float* o = out + (long)which * (Bn * 2048) + (long)b * 2048;
    const int tid = threadIdx.x;
    __shared__ float sm[4], ss[4];

    float m = -3.4e38f;
    for (int i = tid; i < 2048; i += 256) m = fmaxf(m, x[i]);
    for (int off = 32; off > 0; off >>= 1) m = fmaxf(m, __shfl_down(m, off));
    if ((tid & 63) == 0) sm[tid >> 6] = m;
    __syncthreads();
    m = fmaxf(fmaxf(sm[0], sm[1]), fmaxf(sm[2], sm[3]));

    float s = 0.f;
    for (int i = tid; i < 2048; i += 256) s += expf(x[i] - m);
    for (int off = 32; off > 0; off >>= 1) s += __shfl_down(s, off);
    if ((tid & 63) == 0) ss[tid >> 6] = s;
    __syncthreads();
    s = ss[0] + ss[1] + ss[2] + ss[3];
    float inv = 1.0f / s;
    for (int i = tid; i < 2048; i += 256) o[i] = expf(x[i] - m) * inv;
}

__global__ __launch_bounds__(256) void vout_kernel(
    const float* __restrict__ V, const float* __restrict__ av, float* __restrict__ vout)
{
    const int wave = threadIdx.x >> 6, lane = threadIdx.x & 63;
    const long idx = (long)blockIdx.x * 4 + wave;
    const int b = (int)(idx >> 10);
    const int h = (int)(idx & 1023);
    const float* vp = V + ((long)b * Hd + h) * NVn;
    const float* ap = av + (long)b * NVn;
    float s = 0.f;
    for (int i = lane; i < NVn; i += 64) s = fmaf(ap[i], vp[i], s);
    for (int off = 32; off > 0; off >>= 1) s += __shfl_down(s, off);
    if (lane == 0) vout[idx] = s;
}

__global__ __launch_bounds__(256) void qout_kernel(
    const float* __restrict__ Q, const float* __restrict__ aq, float* __restrict__ qout)
{
    const int h  = blockIdx.x * 256 + threadIdx.x;
    const int b  = blockIdx.z;
    const int q0 = blockIdx.y * 256;
    const float* qp = Q + (long)b * NQn * Hd;
    const float* ap = aq + (long)b * NQn + q0;
    float s = 0.f;
    for (int q = 0; q < 256; ++q) s = fmaf(ap[q], qp[(long)(q0 + q) * Hd + h], s);
    atomicAdd(qout + (long)b * Hd + h, s);
}

extern "C" void kernel_launch(void* const* d_in, const int* in_sizes, int n_in,
                              void* d_out, int out_size, void* d_ws, size_t ws_size,
                              hipStream_t stream) {
    const float* V    = (const float*)d_in[0];
    const float* Q    = (const float*)d_in[1];
    const float* W_b  = (const float*)d_in[2];
    const float* W_v  = (const float*)d_in[3];
    const float* W_q  = (const float*)d_in[4];
    const float* w_hv = (const float*)d_in[5];
    const float* w_hq = (const float*)d_in[6];
    float* out = (float*)d_out;
    dim3 blk(256);

    const long BIG  = (long)Bn * Hd * NVn;   // 33.55M elements
    const long GEL  = (long)Bn * Hd * Hd;    // 16.78M
    const long TEL  = (long)Bn * COn * Hd;   // 8.39M
    const long WQE  = (long)COn * Hd;        // 0.52M
    const long WBE  = (long)Hd * Hd;         // 1.05M

    // u16 layout: two big regions (R1 transient, R2 = Q split, alive to the end)
    u16* ws16 = (u16*)d_ws;
    u16* R1h  = ws16;            u16* R1l  = R1h + BIG;      // 134 MB: QT -> VT -> Vs
    u16* R2h  = R1l + BIG;       u16* R2l  = R2h + BIG;      // 134 MB: Q split
    u16* Gh   = R2l + BIG;       u16* Gl   = Gh + GEL;       // 67 MB
    u16* Th   = Gl + GEL;        u16* Tl   = Th + TEL;       // 33.5 MB
    u16* Uh   = Gh;              u16* Ul   = Gh + TEL;       // U aliases dead G
    u16* Wqh  = Tl + TEL;        u16* Wql  = Wqh + WQE;
    u16* Wvh  = Wql + WQE;       u16* Wvl  = Wvh + WQE;
    u16* Wbh  = Wvl + WQE;       u16* Wbl  = Wbh + WBE;
    u16* WbTh = Wbl + WBE;       u16* WbTl = WbTh + WBE;
    float* lv = (float*)(WbTl + WBE);
    float* lq = lv + Bn * NVn;
    const size_t need = (size_t)((u16*)(lq + Bn * NQn) - ws16) * 2;   // 382 MB * ... bytes

    float* vout_p = out + 2 * Bn * NVn;
    float* qout_p = vout_p + Bn * Hd;

    if (ws_size >= need) {
        hipMemsetAsync(lv, 0, (size_t)(Bn * NVn + Bn * NQn) * sizeof(float), stream);
        hipMemsetAsync(qout_p, 0, (size_t)Bn * Hd * sizeof(float), stream);

        // weight splits
        split_kernel<<<dim3((unsigned)(WQE / 1024)), blk, 0, stream>>>(W_q, Wqh, Wql);
        split_kernel<<<dim3((unsigned)(WQE / 1024)), blk, 0, stream>>>(W_v, Wvh, Wvl);
        split_kernel<<<dim3((unsigned)(WBE / 1024)), blk, 0, stream>>>(W_b, Wbh, Wbl);
        tsplit_kernel<<<dim3(Hd / 64, Hd / 64, 1), blk, 0, stream>>>(W_b, WbTh, WbTl, Hd, Hd);

        // ---- chain Q ----
        // fused: QT hi/lo -> R1, Q hi/lo -> R2 (one pass over Q)
        tsplit2_kernel<<<dim3(NQn / 64, Hd / 64, Bn), blk, 0, stream>>>(
            Q, R1h, R1l, R2h, R2l, NQn, Hd);
        // G_Q = QT QT^T  [Hd,Hd]
        mm8p<false><<<dim3((Hd / 256) * (Hd / 256) * Bn), dim3(512), 0, stream>>>(
            R1h, R1l, (long)Hd * NQn, NQn,  R1h, R1l, (long)Hd * NQn, NQn,
            Hd, NQn, Hd / 256, Hd / 256,
            nullptr, Gh, Gl, (long)Hd * Hd, nullptr, nullptr);
        // T = W_q @ G (G symmetric: B = G k-contig)
        mm4<<<dim3(Hd / 128, COn / 128, Bn), blk, 0, stream>>>(
            Wqh, Wql, 0L, Hd,  Gh, Gl, (long)Hd * Hd, Hd,
            Hd, Hd, nullptr, Th, Tl, (long)COn * Hd);
        // U = T @ W_b + W_v  (B = W_b^T pre-transposed)
        mm4<<<dim3(Hd / 128, COn / 128, Bn), blk, 0, stream>>>(
            Th, Tl, (long)COn * Hd, Hd,  WbTh, WbTl, 0L, Hd,
            Hd, Hd, W_v, Uh, Ul, (long)COn * Hd);
        // VT for logits B operand (QT dead)
        tsplit_kernel<<<dim3(Hd / 64, NVn / 64, Bn), blk, 0, stream>>>(V, R1h, R1l, Hd, NVn);
        // logits_v += w_hv . tanh(U @ V)
        mm8p<true><<<dim3((NVn / 256) * (COn / 256) * Bn), dim3(512), 0, stream>>>(
            Uh, Ul, (long)COn * Hd, Hd,  R1h, R1l, (long)NVn * Hd, Hd,
            NVn, Hd, NVn / 256, COn / 256,
            nullptr, nullptr, nullptr, 0L, w_hv, lv);

        // ---- chain V ----
        split_kernel<<<dim3((unsigned)(BIG / 1024)), blk, 0, stream>>>(V, R1h, R1l);
        // G_V = V V^T
        mm8p<false><<<dim3((Hd / 256) * (Hd / 256) * Bn), dim3(512), 0, stream>>>(
            R1h, R1l, (long)Hd * NVn, NVn,  R1h, R1l, (long)Hd * NVn, NVn,
            Hd, NVn, Hd / 256, Hd / 256,
            nullptr, Gh, Gl, (long)Hd * Hd, nullptr, nullptr);
        // T = W_v @ G
        mm4<<<dim3(Hd / 128, COn / 128, Bn), blk, 0, stream>>>(
            Wvh, Wvl, 0L, Hd,  Gh, Gl, (long)Hd * Hd, Hd,
            Hd, Hd, nullptr, Th, Tl, (long)COn * Hd);
        // U = T @ W_b^T + W_q  (B = W_b row-major already [n,k])
        mm4<<<dim3(Hd / 128, COn / 128, Bn), blk, 0, stream>>>(
            Th, Tl, (long)COn * Hd, Hd,  Wbh, Wbl, 0L, Hd,
            Hd, Hd, W_q, Uh, Ul, (long)COn * Hd);
        // logits_q += w_hq . tanh(U @ Q^T)  (B = Q split, still alive in R2)
        mm8p<true><<<dim3((NQn / 256) * (COn / 256) * Bn), dim3(512), 0, stream>>>(
            Uh, Ul, (long)COn * Hd, Hd,  R2h, R2l, (long)NQn * Hd, Hd,
            NQn, Hd, NQn / 256, COn / 256,
            nullptr, nullptr, nullptr, 0L, w_hq, lq);

        softmax_kernel<<<dim3(Bn, 2), blk, 0, stream>>>(lv, lq, out);
        vout_kernel<<<dim3(Bn * Hd / 4), blk, 0, stream>>>(V, out, vout_p);
        qout_kernel<<<dim3(Hd / 256, NQn / 256, Bn), blk, 0, stream>>>(Q, out + Bn * NVn, qout_p);
        return;
    }

    // ---------------- fp32 fallback tier ----------------
    float* ws = (float*)d_ws;
    float* g  = ws;
    float* t  = g + GEL;
    float* u  = t + TEL;
    float* flv = u + TEL;
    float* flq = flv + Bn * NVn;

    hipMemsetAsync(flv, 0, (size_t)(Bn * NVn + Bn * NQn) * sizeof(float), stream);
    hipMemsetAsync(qout_p, 0, (size_t)Bn * Hd * sizeof(float), stream);

    gemm_core<false><<<dim3(Hd/BN, Hd/BM, Bn), blk, 0, stream>>>(Q, Q, g, nullptr,
        Hd, Hd, NQn, 1, Hd, (long)NQn*Hd, Hd, 1, (long)NQn*Hd, (long)Hd*Hd, nullptr, nullptr);
    gemm_core<false><<<dim3(Hd/BN, COn/BM, Bn), blk, 0, stream>>>(W_q, g, t, nullptr,
        COn, Hd, Hd, Hd, 1, 0L, Hd, 1, (long)Hd*Hd, (long)COn*Hd, nullptr, nullptr);
    gemm_core<false><<<dim3(Hd/BN, COn/BM, Bn), blk, 0, stream>>>(t, W_b, u, W_v,
        COn, Hd, Hd, Hd, 1, (long)COn*Hd, Hd, 1, 0L, (long)COn*Hd, nullptr, nullptr);
    gemm_core<true><<<dim3(NVn/BN, COn/BM, Bn), blk, 0, stream>>>(
        u, V, nullptr, nullptr, COn, NVn, Hd,
        Hd, 1, (long)COn*Hd, NVn, 1, (long)Hd*NVn, 0L, w_hv, flv);
    gemm_core<false><<<dim3(Hd/BN, Hd/BM, Bn), blk, 0, stream>>>(V, V, g, nullptr,
        Hd, Hd, NVn, NVn, 1, (long)Hd*NVn, 1, NVn, (long)Hd*NVn, (long)Hd*Hd, nullptr, nullptr);
    gemm_core<false><<<dim3(Hd/BN, COn/BM, Bn), blk, 0, stream>>>(W_v, g, t, nullptr,
        COn, Hd, Hd, Hd, 1, 0L, Hd, 1, (long)Hd*Hd, (long)COn*Hd, nullptr, nullptr);
    gemm_core<false><<<dim3(Hd/BN, COn/BM, Bn), blk, 0, stream>>>(t, W_b, u, W_q,
        COn, Hd, Hd, Hd, 1, (long)COn*Hd, 1, Hd, 0L, (long)COn*Hd, nullptr, nullptr);
    gemm_core<true><<<dim3(NQn/BN, COn/BM, Bn), blk, 0, stream>>>(
        u, Q, nullptr, nullptr, COn, NQn, Hd,
        Hd, 1, (long)COn*Hd, 1, Hd, (long)NQn*Hd, 0L, w_hq, flq);

    softmax_kernel<<<dim3(Bn, 2), blk, 0, stream>>>(flv, flq, out);
    vout_kernel<<<dim3(Bn * Hd / 4), blk, 0, stream>>>(V, out, vout_p);
    qout_kernel<<<dim3(Hd / 256, NQn / 256, Bn), blk, 0, stream>>>(Q, out + Bn * NVn, qout_p);
}